// Round 11
// baseline (174.047 us; speedup 1.0000x reference)
//
#include <hip/hip_runtime.h>
#include <math.h>

#define T_LEN 4096
#define D_IN 128
#define KDIM 4096   // TR*CTX
#define K2   8192   // re+im
#define NBLK 256

// ws float offsets
#define OFF_GATED 0u
#define OFF_GO    262144u
#define OFF_SKIP  524288u
#define OFF_PART  786432u          // 16 * 262144 partials
#define OFF_FLAGS 4980736u         // 4096 ints
#define OFF_CHS   4984832u         // 64 ints
#define OFF_WZT   4984896u         // 524288 bf16 = 262144 float slots
#define OFF_SCR   5247040u         // carryB 524288 + cinArr 524288 floats
#define OFF_BAR   6295616u         // barrier ints (64)

typedef __attribute__((ext_vector_type(8))) short short8v;
typedef __attribute__((ext_vector_type(4))) float float4v;

__device__ __forceinline__ float sigm(float x){ return 1.f/(1.f+expf(-x)); }
__device__ __forceinline__ unsigned short f2bf(float x){
    unsigned int u = __float_as_uint(x);
    return (unsigned short)((u + 0x7FFFu + ((u >> 16) & 1u)) >> 16);
}
__device__ __forceinline__ float wsum(float v) {
#pragma unroll
    for (int o = 32; o; o >>= 1) v += __shfl_xor(v, o, 64);
    return v;
}

struct Params {
    const unsigned char* su8; const int* si32;
    const float *x, *st0, *a, *b;
    const float *W1,*b1,*W2,*b2,*Wgi,*bgi,*Wp,*bp,*Wz,*bz,*Wgo,*bgo,*Wsk,*bsk,*W3,*b3,*W4,*b4;
    float *gated,*go,*sk,*part; int *flags,*chs; unsigned short* wzt;
    float2 *carryB,*cinArr; float* out; int* bar;
};

// grid barrier: all 256 blocks co-resident (<=1 CU of resources each).
// Arrival = one atomicAdd per block; POLL = coherent atomic LOAD (no RMW flood).
__device__ __forceinline__ void gsync(int* bar) {
    __syncthreads();
    if (threadIdx.x == 0) {
        __threadfence();                 // release: flush my block's writes
        atomicAdd(bar, 1);
        while (__hip_atomic_load(bar, __ATOMIC_RELAXED, __HIP_MEMORY_SCOPE_AGENT) < NBLK)
            __builtin_amdgcn_s_sleep(16);
        __threadfence();                 // acquire: discard stale cached lines
    }
    __syncthreads();
}

__global__ __launch_bounds__(512) void k_mega(Params P) {
    __shared__ __align__(16) char smem[65536];
    const int bx = blockIdx.x;
    const int tid = threadIdx.x;

    // ================= P0: flags | wzt | mlp =================
    if (bx == 0) {
        int* cnt = (int*)(smem + 20480);
        if (tid == 0) *cnt = 0;
        __syncthreads();
        int local = 0;
        for (int i = tid; i < 4096; i += 512)
            if (i & 3) local += P.su8[i];
        if (local) atomicAdd(cnt, local);
        __syncthreads();
        if (*cnt > 0) { for (int i = tid; i < 4096; i += 512) P.flags[i] = P.su8[i] ? 1 : 0; }
        else          { for (int i = tid; i < 4096; i += 512) P.flags[i] = P.si32[i] ? 1 : 0; }
        __syncthreads();
        if (tid < 64) {
            int any = 0;
#pragma unroll 8
            for (int j = 0; j < 64; ++j) any |= P.flags[tid * 64 + j];
            P.chs[tid] = any;
        }
    }
    if (bx >= 1 && bx <= 64) {   // wzt[j][k] = bf16(Wz[k][j])
        int idx = ((bx - 1) * 512 + tid) * 16;
        int j = idx >> 13, k0 = idx & 8191;
#pragma unroll
        for (int e = 0; e < 16; ++e) {
            int k = k0 + e;
            P.wzt[(size_t)j * K2 + k] = f2bf(P.Wz[(size_t)k * 64 + j]);
        }
    }
    {   // mlp: 2 units of 8 rows per block, weights hoisted in VGPRs
        float (*xs)[128]  = (float(*)[128])smem;
        float (*hs)[64]   = (float(*)[64])(smem + 4096);
        float (*h2s)[128] = (float(*)[128])(smem + 6144);
        float (*tmp)[4][64] = (float(*)[4][64])(smem + 10240);

        const int j1 = tid >> 3, ks1 = tid & 7;
        float wr1[16];
#pragma unroll
        for (int kk = 0; kk < 16; ++kk) wr1[kk] = P.W1[(size_t)(ks1 * 16 + kk) * 64 + j1];
        const float bias1 = P.b1[j1];
        const int j2 = tid >> 2, ks2 = tid & 3;
        float wr2[16];
#pragma unroll
        for (int kk = 0; kk < 16; ++kk) wr2[kk] = P.W2[(size_t)(ks2 * 16 + kk) * 128 + j2];
        const float bias2 = P.b2[j2];
        const int mat = tid >> 7, jj = (tid & 127) >> 1, kh = tid & 1;
        const float* Wm = (mat == 0) ? P.Wgi : (mat == 1) ? P.Wp : (mat == 2) ? P.Wgo : P.Wsk;
        float wgr[64];
#pragma unroll
        for (int kk = 0; kk < 64; ++kk) wgr[kk] = Wm[(size_t)(kh * 64 + kk) * 64 + jj];

        for (int u = 0; u < 2; ++u) {
            const int t0 = (bx * 2 + u) * 8;
            __syncthreads();
            if (tid < 256) {
                int r = tid >> 5, kq = (tid & 31) << 2;
                *(float4*)&xs[r][kq] = *(const float4*)&P.x[(size_t)(t0 + r) * D_IN + kq];
            }
            __syncthreads();
#pragma unroll
            for (int r = 0; r < 8; ++r) {
                float p = 0.f;
#pragma unroll
                for (int kq = 0; kq < 4; ++kq) {
                    float4 xv = *(const float4*)&xs[r][ks1 * 16 + kq * 4];
                    p += xv.x*wr1[kq*4] + xv.y*wr1[kq*4+1] + xv.z*wr1[kq*4+2] + xv.w*wr1[kq*4+3];
                }
                p += __shfl_xor(p, 1, 64); p += __shfl_xor(p, 2, 64); p += __shfl_xor(p, 4, 64);
                if (ks1 == 0) hs[r][j1] = fmaxf(p + bias1, 0.f);
            }
            __syncthreads();
#pragma unroll
            for (int r = 0; r < 8; ++r) {
                float p = 0.f;
#pragma unroll
                for (int kq = 0; kq < 4; ++kq) {
                    float4 hv = *(const float4*)&hs[r][ks2 * 16 + kq * 4];
                    p += hv.x*wr2[kq*4] + hv.y*wr2[kq*4+1] + hv.z*wr2[kq*4+2] + hv.w*wr2[kq*4+3];
                }
                p += __shfl_xor(p, 1, 64); p += __shfl_xor(p, 2, 64);
                if (ks2 == 0) h2s[r][j2] = p + bias2;
            }
            __syncthreads();
#pragma unroll
            for (int r = 0; r < 8; ++r) {
                float p = 0.f;
#pragma unroll
                for (int kq = 0; kq < 16; ++kq) {
                    float4 hv = *(const float4*)&h2s[r][kh * 64 + kq * 4];
                    p += hv.x*wgr[kq*4] + hv.y*wgr[kq*4+1] + hv.z*wgr[kq*4+2] + hv.w*wgr[kq*4+3];
                }
                p += __shfl_xor(p, 1, 64);
                if (kh == 0) tmp[r][mat][jj] = p;
            }
            __syncthreads();
            {
                int r = tid >> 6, j = tid & 63;
                int t = t0 + r;
                float gi = sigm(tmp[r][0][j] + P.bgi[j]);
                float pr = sigm(tmp[r][1][j] + P.bp[j]);
                float g  = sigm(tmp[r][2][j] + P.bgo[j]);
                float s  = tmp[r][3][j] + P.bsk[j];
                P.gated[t * 64 + j] = gi * pr;
                P.go[t * 64 + j]    = g;
                P.sk[t * 64 + j]    = s;
            }
        }
    }
    gsync(P.bar + 0);

    // ================= P1: scanA (per-chunk local carries) =================
    {
        const int p = tid >> 6, c = tid & 63;
#pragma unroll
        for (int u = 0; u < 2; ++u) {
            const int pair = (bx * 2 + u) * 8 + p;
            const int ch = pair & 63, m = pair >> 6, t0s = ch * 64;
            const double ea = exp(-fabs((double)P.a[m]));
            const double bb = (double)P.b[c];
            const double lre = ea * cos(bb), lim = ea * sin(bb);
            float gv = P.gated[(size_t)(t0s + c) * 64 + m];
            unsigned long long fmask = __ballot(P.flags[t0s + c] != 0);
            double sre = 0.0, sim = 0.0;
#pragma unroll 8
            for (int j = 0; j < 64; ++j) {
                double g = (double)__shfl(gv, j, 64);
                if ((fmask >> j) & 1) { sre = g; sim = 0.0; }
                else {
                    double nr = fma(sre, lre, fma(-sim, lim, g));
                    double ni = fma(sre, lim, sim * lre);
                    sre = nr; sim = ni;
                }
            }
            P.carryB[(size_t)ch * KDIM + m * 64 + c] = make_float2((float)sre, (float)sim);
        }
    }
    gsync(P.bar + 16);

    // ================= P2: scanC (carry scan over chunks) =================
    if (bx < 64 && tid < 64) {
        const int m = bx, c = tid;
        unsigned long long cmask = __ballot(P.chs[c] != 0);
        float2 Bv[64];
#pragma unroll
        for (int ch = 0; ch < 64; ++ch)
            Bv[ch] = P.carryB[(size_t)ch * KDIM + m * 64 + c];
        const double ea64 = exp(-64.0 * fabs((double)P.a[m]));
        const double bb = (double)P.b[c];
        const double l64re = ea64 * cos(64.0 * bb), l64im = ea64 * sin(64.0 * bb);
        double cre = (double)P.st0[(m * 64 + c) * 2];
        double cim = (double)P.st0[(m * 64 + c) * 2 + 1];
#pragma unroll
        for (int ch = 0; ch < 64; ++ch) {
            P.cinArr[(size_t)ch * KDIM + m * 64 + c] = make_float2((float)cre, (float)cim);
            if ((cmask >> ch) & 1) { cre = (double)Bv[ch].x; cim = (double)Bv[ch].y; }
            else {
                double nr = fma(cre, l64re, fma(-cim, l64im, (double)Bv[ch].x));
                double ni = fma(cre, l64im, fma(cim, l64re, (double)Bv[ch].y));
                cre = nr; cim = ni;
            }
        }
    }
    gsync(P.bar + 32);

    // ================= P3: scanBZ (seeded scan -> LDS tile -> MFMA) =================
    {
        unsigned short* st = (unsigned short*)smem;
        const int w = tid >> 6, l = tid & 63;
        const int ml = w & 3, mth = w >> 2;
        for (int u = 0; u < 4; ++u) {
            const int pair = bx * 4 + u;
            const int ch = pair & 63, mg = pair >> 6, t0s = ch * 64;
            const int m = mg * 4 + ml;
            const int jrow = ml * 16 + (l & 15);
            short8v bfr[16];
#pragma unroll
            for (int ks = 0; ks < 16; ++ks)
                bfr[ks] = *(const short8v*)&P.wzt[(size_t)jrow * K2 + mg * 512 + (ks * 4 + (l >> 4)) * 8];
            __syncthreads();   // previous iteration's MFMA reads finished before overwriting st
            if (w < 4) {
                const double ea = exp(-fabs((double)P.a[m]));
                const double bb = (double)P.b[l];
                const double lre = ea * cos(bb), lim = ea * sin(bb);
                float gv = P.gated[(size_t)(t0s + l) * 64 + m];
                unsigned long long fmask = __ballot(P.flags[t0s + l] != 0);
                float2 cin = P.cinArr[(size_t)ch * KDIM + m * 64 + l];
                double sre = (double)cin.x, sim = (double)cin.y;
                const int e0 = ml * 128 + l, e1 = e0 + 64;
#pragma unroll 4
                for (int j = 0; j < 64; ++j) {
                    double g = (double)__shfl(gv, j, 64);
                    if ((fmask >> j) & 1) { sre = g; sim = 0.0; }
                    else {
                        double nr = fma(sre, lre, fma(-sim, lim, g));
                        double ni = fma(sre, lim, sim * lre);
                        sre = nr; sim = ni;
                    }
                    const int sx = (j & 7) << 3;
                    st[j * 512 + (e0 ^ sx)] = f2bf((float)sre);
                    st[j * 512 + (e1 ^ sx)] = f2bf((float)sim);
                }
                if (ch == 63) {
                    P.out[524288 + m * 64 + l]        = (float)sre;
                    P.out[524288 + 4096 + m * 64 + l] = (float)sim;
                }
            }
            __syncthreads();
            float4v acc[2];
            acc[0] = (float4v){0.f,0.f,0.f,0.f};
            acc[1] = (float4v){0.f,0.f,0.f,0.f};
#pragma unroll
            for (int ks = 0; ks < 16; ++ks) {
#pragma unroll
                for (int q = 0; q < 2; ++q) {
                    const int row = (mth * 2 + q) * 16 + (l & 15);
                    const int rchunk = (ks * 4 + (l >> 4)) ^ (row & 7);
                    short8v af = *(const short8v*)&st[row * 512 + rchunk * 8];
                    acc[q] = __builtin_amdgcn_mfma_f32_16x16x32_bf16(af, bfr[ks], acc[q], 0, 0, 0);
                }
            }
            float* pp = P.part + (size_t)mg * 262144;
            const int jcol = ml * 16 + (l & 15);
#pragma unroll
            for (int q = 0; q < 2; ++q) {
                const int trow = t0s + (mth * 2 + q) * 16 + (l >> 4) * 4;
#pragma unroll
                for (int r = 0; r < 4; ++r)
                    pp[(size_t)(trow + r) * 64 + jcol] = acc[q][r];
            }
        }
    }
    gsync(P.bar + 48);

    // ================= P4: epilogue (16 rows/block, wave-private LDS) =================
    {
        float (*ob)[64] = (float(*)[64])smem;
        float (*hb)[64] = (float(*)[64])(smem + 2048);
        const int w = tid >> 6, j = tid & 63;
        for (int it = 0; it < 2; ++it) {
            const int t = bx * 16 + it * 8 + w;
            float z = P.bz[j];
#pragma unroll
            for (int p = 0; p < 16; ++p) z += P.part[(size_t)p * 262144 + t * 64 + j];
            float g = P.go[t * 64 + j];
            float y = z * g;
            float mu = wsum(y) * 0.015625f;
            float d = y - mu;
            float var = wsum(d * d) * 0.015625f;
            float o = d * (1.f / sqrtf(var + 1e-6f)) + P.sk[t * 64 + j] * (1.f - g);
            ob[w][j] = o;
            float acc2 = P.b3[j];
#pragma unroll 8
            for (int k = 0; k < 64; ++k) acc2 += ob[w][k] * P.W3[k * 64 + j];
            hb[w][j] = fmaxf(acc2, 0.f);
            float o1 = P.b4[j], o2 = P.b4[j + 64];
#pragma unroll 8
            for (int k = 0; k < 64; ++k) { float hv = hb[w][k]; o1 += hv * P.W4[k * 128 + j]; o2 += hv * P.W4[k * 128 + j + 64]; }
            P.out[(size_t)t * 128 + j] = o1;
            P.out[(size_t)t * 128 + j + 64] = o2;
        }
    }
}

// ----------------------------------------------------------------
extern "C" void kernel_launch(void* const* d_in, const int* in_sizes, int n_in,
                              void* d_out, int out_size, void* d_ws, size_t ws_size,
                              hipStream_t stream)
{
    float* ws = (float*)d_ws;
    Params P;
    P.su8 = (const unsigned char*)d_in[2];
    P.si32 = (const int*)d_in[2];
    P.x   = (const float*)d_in[0];
    P.st0 = (const float*)d_in[1];
    P.a   = (const float*)d_in[3];
    P.b   = (const float*)d_in[4];
    P.W1  = (const float*)d_in[5];  P.b1  = (const float*)d_in[6];
    P.W2  = (const float*)d_in[7];  P.b2  = (const float*)d_in[8];
    P.Wgi = (const float*)d_in[9];  P.bgi = (const float*)d_in[10];
    P.Wp  = (const float*)d_in[11]; P.bp  = (const float*)d_in[12];
    P.Wz  = (const float*)d_in[13]; P.bz  = (const float*)d_in[14];
    P.Wgo = (const float*)d_in[15]; P.bgo = (const float*)d_in[16];
    P.Wsk = (const float*)d_in[17]; P.bsk = (const float*)d_in[18];
    P.W3  = (const float*)d_in[19]; P.b3  = (const float*)d_in[20];
    P.W4  = (const float*)d_in[21]; P.b4  = (const float*)d_in[22];
    P.gated = ws + OFF_GATED;
    P.go    = ws + OFF_GO;
    P.sk    = ws + OFF_SKIP;
    P.part  = ws + OFF_PART;
    P.flags = (int*)(ws + OFF_FLAGS);
    P.chs   = (int*)(ws + OFF_CHS);
    P.wzt   = (unsigned short*)(ws + OFF_WZT);
    P.carryB = (float2*)(ws + OFF_SCR);
    P.cinArr = (float2*)(ws + OFF_SCR + 524288);
    P.out   = (float*)d_out;
    P.bar   = (int*)(ws + OFF_BAR);

    hipMemsetAsync(P.bar, 0, 64 * sizeof(int), stream);
    hipLaunchKernelGGL(k_mega, dim3(NBLK), dim3(512), 0, stream, P);
}

// Round 12
// 146.307 us; speedup vs baseline: 1.1896x; 1.1896x over previous
//
#include <hip/hip_runtime.h>
#include <math.h>

#define T_LEN 4096
#define D_IN 128
#define KDIM 4096   // TR*CTX
#define K2   8192   // re+im
#define NBLK 256

// ws float offsets
#define OFF_GATED 0u
#define OFF_GO    262144u
#define OFF_SKIP  524288u
#define OFF_PART  786432u          // 16 * 262144 partials
#define OFF_FLAGS 4980736u         // 4096 ints
#define OFF_CHS   4984832u         // 64 ints
#define OFF_WZT   4984896u         // 524288 bf16 = 262144 float slots
#define OFF_SCR   5247040u         // carryB 524288 + cinArr 524288 floats
#define OFF_BAR   6295616u         // arrival flags 256*32 ints + go word

typedef __attribute__((ext_vector_type(8))) short short8v;
typedef __attribute__((ext_vector_type(4))) float float4v;

__device__ __forceinline__ float sigm(float x){ return 1.f/(1.f+expf(-x)); }
__device__ __forceinline__ unsigned short f2bf(float x){
    unsigned int u = __float_as_uint(x);
    return (unsigned short)((u + 0x7FFFu + ((u >> 16) & 1u)) >> 16);
}
__device__ __forceinline__ float wsum(float v) {
#pragma unroll
    for (int o = 32; o; o >>= 1) v += __shfl_xor(v, o, 64);
    return v;
}

struct Params {
    const unsigned char* su8; const int* si32;
    const float *x, *st0, *a, *b;
    const float *W1,*b1,*W2,*b2,*Wgi,*bgi,*Wp,*bp,*Wz,*bz,*Wgo,*bgo,*Wsk,*bsk,*W3,*b3,*W4,*b4;
    float *gated,*go,*sk,*part; int *flags,*chs; unsigned short* wzt;
    float2 *carryB,*cinArr; float* out; int* arr; int* gow;
};

// grid barrier, contention-free: per-block arrival flag (own cacheline, plain
// atomic STORE), block 0 detects via 256 parallel pollers, releases one go word;
// others poll go with read-only loads. Epoch-numbered; ws zeroed each launch.
__device__ __forceinline__ void gsync(int* arr, int* gow, int epoch) {
    __syncthreads();
    if (threadIdx.x == 0) {
        __threadfence();   // release: my block's writes visible device-wide
        __hip_atomic_store(arr + blockIdx.x * 32, epoch,
                           __ATOMIC_RELAXED, __HIP_MEMORY_SCOPE_AGENT);
    }
    if (blockIdx.x == 0) {
        if (threadIdx.x < NBLK) {
            while (__hip_atomic_load(arr + threadIdx.x * 32,
                                     __ATOMIC_RELAXED, __HIP_MEMORY_SCOPE_AGENT) < epoch)
                __builtin_amdgcn_s_sleep(2);
        }
        __syncthreads();
        if (threadIdx.x == 0) {
            __threadfence();   // acquire (all arrivals seen) + release for go
            __hip_atomic_store(gow, epoch, __ATOMIC_RELAXED, __HIP_MEMORY_SCOPE_AGENT);
        }
    } else {
        if (threadIdx.x == 0) {
            while (__hip_atomic_load(gow, __ATOMIC_RELAXED,
                                     __HIP_MEMORY_SCOPE_AGENT) < epoch)
                __builtin_amdgcn_s_sleep(2);
            __threadfence();   // acquire: discard stale cached lines
        }
    }
    __syncthreads();
}

__global__ __launch_bounds__(512) void k_mega(Params P) {
    __shared__ __align__(16) char smem[65536];
    const int bx = blockIdx.x;
    const int tid = threadIdx.x;

    // ================= P0: flags | wzt | mlp =================
    if (bx == 0) {
        int* cnt = (int*)(smem + 20480);
        if (tid == 0) *cnt = 0;
        __syncthreads();
        int local = 0;
        for (int i = tid; i < 4096; i += 512)
            if (i & 3) local += P.su8[i];
        if (local) atomicAdd(cnt, local);
        __syncthreads();
        if (*cnt > 0) { for (int i = tid; i < 4096; i += 512) P.flags[i] = P.su8[i] ? 1 : 0; }
        else          { for (int i = tid; i < 4096; i += 512) P.flags[i] = P.si32[i] ? 1 : 0; }
        __syncthreads();
        if (tid < 64) {
            int any = 0;
#pragma unroll 8
            for (int j = 0; j < 64; ++j) any |= P.flags[tid * 64 + j];
            P.chs[tid] = any;
        }
    }
    if (bx >= 1 && bx <= 64) {   // wzt[j][k] = bf16(Wz[k][j])
        int idx = ((bx - 1) * 512 + tid) * 16;
        int j = idx >> 13, k0 = idx & 8191;
#pragma unroll
        for (int e = 0; e < 16; ++e) {
            int k = k0 + e;
            P.wzt[(size_t)j * K2 + k] = f2bf(P.Wz[(size_t)k * 64 + j]);
        }
    }
    {   // mlp: 2 units of 8 rows per block, weights hoisted in VGPRs
        float (*xs)[128]  = (float(*)[128])smem;
        float (*hs)[64]   = (float(*)[64])(smem + 4096);
        float (*h2s)[128] = (float(*)[128])(smem + 6144);
        float (*tmp)[4][64] = (float(*)[4][64])(smem + 10240);

        const int j1 = tid >> 3, ks1 = tid & 7;
        float wr1[16];
#pragma unroll
        for (int kk = 0; kk < 16; ++kk) wr1[kk] = P.W1[(size_t)(ks1 * 16 + kk) * 64 + j1];
        const float bias1 = P.b1[j1];
        const int j2 = tid >> 2, ks2 = tid & 3;
        float wr2[16];
#pragma unroll
        for (int kk = 0; kk < 16; ++kk) wr2[kk] = P.W2[(size_t)(ks2 * 16 + kk) * 128 + j2];
        const float bias2 = P.b2[j2];
        const int mat = tid >> 7, jj = (tid & 127) >> 1, kh = tid & 1;
        const float* Wm = (mat == 0) ? P.Wgi : (mat == 1) ? P.Wp : (mat == 2) ? P.Wgo : P.Wsk;
        float wgr[64];
#pragma unroll
        for (int kk = 0; kk < 64; ++kk) wgr[kk] = Wm[(size_t)(kh * 64 + kk) * 64 + jj];

        for (int u = 0; u < 2; ++u) {
            const int t0 = (bx * 2 + u) * 8;
            __syncthreads();
            if (tid < 256) {
                int r = tid >> 5, kq = (tid & 31) << 2;
                *(float4*)&xs[r][kq] = *(const float4*)&P.x[(size_t)(t0 + r) * D_IN + kq];
            }
            __syncthreads();
#pragma unroll
            for (int r = 0; r < 8; ++r) {
                float p = 0.f;
#pragma unroll
                for (int kq = 0; kq < 4; ++kq) {
                    float4 xv = *(const float4*)&xs[r][ks1 * 16 + kq * 4];
                    p += xv.x*wr1[kq*4] + xv.y*wr1[kq*4+1] + xv.z*wr1[kq*4+2] + xv.w*wr1[kq*4+3];
                }
                p += __shfl_xor(p, 1, 64); p += __shfl_xor(p, 2, 64); p += __shfl_xor(p, 4, 64);
                if (ks1 == 0) hs[r][j1] = fmaxf(p + bias1, 0.f);
            }
            __syncthreads();
#pragma unroll
            for (int r = 0; r < 8; ++r) {
                float p = 0.f;
#pragma unroll
                for (int kq = 0; kq < 4; ++kq) {
                    float4 hv = *(const float4*)&hs[r][ks2 * 16 + kq * 4];
                    p += hv.x*wr2[kq*4] + hv.y*wr2[kq*4+1] + hv.z*wr2[kq*4+2] + hv.w*wr2[kq*4+3];
                }
                p += __shfl_xor(p, 1, 64); p += __shfl_xor(p, 2, 64);
                if (ks2 == 0) h2s[r][j2] = p + bias2;
            }
            __syncthreads();
#pragma unroll
            for (int r = 0; r < 8; ++r) {
                float p = 0.f;
#pragma unroll
                for (int kq = 0; kq < 16; ++kq) {
                    float4 hv = *(const float4*)&h2s[r][kh * 64 + kq * 4];
                    p += hv.x*wgr[kq*4] + hv.y*wgr[kq*4+1] + hv.z*wgr[kq*4+2] + hv.w*wgr[kq*4+3];
                }
                p += __shfl_xor(p, 1, 64);
                if (kh == 0) tmp[r][mat][jj] = p;
            }
            __syncthreads();
            {
                int r = tid >> 6, j = tid & 63;
                int t = t0 + r;
                float gi = sigm(tmp[r][0][j] + P.bgi[j]);
                float pr = sigm(tmp[r][1][j] + P.bp[j]);
                float g  = sigm(tmp[r][2][j] + P.bgo[j]);
                float s  = tmp[r][3][j] + P.bsk[j];
                P.gated[t * 64 + j] = gi * pr;
                P.go[t * 64 + j]    = g;
                P.sk[t * 64 + j]    = s;
            }
        }
    }
    gsync(P.arr, P.gow, 1);

    // ================= P1: scanA (per-chunk local carries) =================
    {
        const int p = tid >> 6, c = tid & 63;
#pragma unroll
        for (int u = 0; u < 2; ++u) {
            const int pair = (bx * 2 + u) * 8 + p;
            const int ch = pair & 63, m = pair >> 6, t0s = ch * 64;
            const double ea = exp(-fabs((double)P.a[m]));
            const double bb = (double)P.b[c];
            const double lre = ea * cos(bb), lim = ea * sin(bb);
            float gv = P.gated[(size_t)(t0s + c) * 64 + m];
            unsigned long long fmask = __ballot(P.flags[t0s + c] != 0);
            double sre = 0.0, sim = 0.0;
#pragma unroll 8
            for (int j = 0; j < 64; ++j) {
                double g = (double)__shfl(gv, j, 64);
                if ((fmask >> j) & 1) { sre = g; sim = 0.0; }
                else {
                    double nr = fma(sre, lre, fma(-sim, lim, g));
                    double ni = fma(sre, lim, sim * lre);
                    sre = nr; sim = ni;
                }
            }
            P.carryB[(size_t)ch * KDIM + m * 64 + c] = make_float2((float)sre, (float)sim);
        }
    }
    gsync(P.arr, P.gow, 2);

    // ================= P2: scanC (carry scan over chunks) =================
    if (bx < 64 && tid < 64) {
        const int m = bx, c = tid;
        unsigned long long cmask = __ballot(P.chs[c] != 0);
        float2 Bv[64];
#pragma unroll
        for (int ch = 0; ch < 64; ++ch)
            Bv[ch] = P.carryB[(size_t)ch * KDIM + m * 64 + c];
        const double ea64 = exp(-64.0 * fabs((double)P.a[m]));
        const double bb = (double)P.b[c];
        const double l64re = ea64 * cos(64.0 * bb), l64im = ea64 * sin(64.0 * bb);
        double cre = (double)P.st0[(m * 64 + c) * 2];
        double cim = (double)P.st0[(m * 64 + c) * 2 + 1];
#pragma unroll
        for (int ch = 0; ch < 64; ++ch) {
            P.cinArr[(size_t)ch * KDIM + m * 64 + c] = make_float2((float)cre, (float)cim);
            if ((cmask >> ch) & 1) { cre = (double)Bv[ch].x; cim = (double)Bv[ch].y; }
            else {
                double nr = fma(cre, l64re, fma(-cim, l64im, (double)Bv[ch].x));
                double ni = fma(cre, l64im, fma(cim, l64re, (double)Bv[ch].y));
                cre = nr; cim = ni;
            }
        }
    }
    gsync(P.arr, P.gow, 3);

    // ================= P3: scanBZ (seeded scan -> LDS tile -> MFMA) =================
    {
        unsigned short* st = (unsigned short*)smem;
        const int w = tid >> 6, l = tid & 63;
        const int ml = w & 3, mth = w >> 2;
        for (int u = 0; u < 4; ++u) {
            const int pair = bx * 4 + u;
            const int ch = pair & 63, mg = pair >> 6, t0s = ch * 64;
            const int m = mg * 4 + ml;
            const int jrow = ml * 16 + (l & 15);
            short8v bfr[16];
#pragma unroll
            for (int ks = 0; ks < 16; ++ks)
                bfr[ks] = *(const short8v*)&P.wzt[(size_t)jrow * K2 + mg * 512 + (ks * 4 + (l >> 4)) * 8];
            __syncthreads();   // previous iteration's MFMA reads finished before overwriting st
            if (w < 4) {
                const double ea = exp(-fabs((double)P.a[m]));
                const double bb = (double)P.b[l];
                const double lre = ea * cos(bb), lim = ea * sin(bb);
                float gv = P.gated[(size_t)(t0s + l) * 64 + m];
                unsigned long long fmask = __ballot(P.flags[t0s + l] != 0);
                float2 cin = P.cinArr[(size_t)ch * KDIM + m * 64 + l];
                double sre = (double)cin.x, sim = (double)cin.y;
                const int e0 = ml * 128 + l, e1 = e0 + 64;
#pragma unroll 4
                for (int j = 0; j < 64; ++j) {
                    double g = (double)__shfl(gv, j, 64);
                    if ((fmask >> j) & 1) { sre = g; sim = 0.0; }
                    else {
                        double nr = fma(sre, lre, fma(-sim, lim, g));
                        double ni = fma(sre, lim, sim * lre);
                        sre = nr; sim = ni;
                    }
                    const int sx = (j & 7) << 3;
                    st[j * 512 + (e0 ^ sx)] = f2bf((float)sre);
                    st[j * 512 + (e1 ^ sx)] = f2bf((float)sim);
                }
                if (ch == 63) {
                    P.out[524288 + m * 64 + l]        = (float)sre;
                    P.out[524288 + 4096 + m * 64 + l] = (float)sim;
                }
            }
            __syncthreads();
            float4v acc[2];
            acc[0] = (float4v){0.f,0.f,0.f,0.f};
            acc[1] = (float4v){0.f,0.f,0.f,0.f};
#pragma unroll
            for (int ks = 0; ks < 16; ++ks) {
#pragma unroll
                for (int q = 0; q < 2; ++q) {
                    const int row = (mth * 2 + q) * 16 + (l & 15);
                    const int rchunk = (ks * 4 + (l >> 4)) ^ (row & 7);
                    short8v af = *(const short8v*)&st[row * 512 + rchunk * 8];
                    acc[q] = __builtin_amdgcn_mfma_f32_16x16x32_bf16(af, bfr[ks], acc[q], 0, 0, 0);
                }
            }
            float* pp = P.part + (size_t)mg * 262144;
            const int jcol = ml * 16 + (l & 15);
#pragma unroll
            for (int q = 0; q < 2; ++q) {
                const int trow = t0s + (mth * 2 + q) * 16 + (l >> 4) * 4;
#pragma unroll
                for (int r = 0; r < 4; ++r)
                    pp[(size_t)(trow + r) * 64 + jcol] = acc[q][r];
            }
        }
    }
    gsync(P.arr, P.gow, 4);

    // ================= P4: epilogue (16 rows/block, wave-private LDS) =================
    {
        float (*ob)[64] = (float(*)[64])smem;
        float (*hb)[64] = (float(*)[64])(smem + 2048);
        const int w = tid >> 6, j = tid & 63;
        for (int it = 0; it < 2; ++it) {
            const int t = bx * 16 + it * 8 + w;
            float z = P.bz[j];
#pragma unroll
            for (int p = 0; p < 16; ++p) z += P.part[(size_t)p * 262144 + t * 64 + j];
            float g = P.go[t * 64 + j];
            float y = z * g;
            float mu = wsum(y) * 0.015625f;
            float d = y - mu;
            float var = wsum(d * d) * 0.015625f;
            float o = d * (1.f / sqrtf(var + 1e-6f)) + P.sk[t * 64 + j] * (1.f - g);
            ob[w][j] = o;
            float acc2 = P.b3[j];
#pragma unroll 8
            for (int k = 0; k < 64; ++k) acc2 += ob[w][k] * P.W3[k * 64 + j];
            hb[w][j] = fmaxf(acc2, 0.f);
            float o1 = P.b4[j], o2 = P.b4[j + 64];
#pragma unroll 8
            for (int k = 0; k < 64; ++k) { float hv = hb[w][k]; o1 += hv * P.W4[k * 128 + j]; o2 += hv * P.W4[k * 128 + j + 64]; }
            P.out[(size_t)t * 128 + j] = o1;
            P.out[(size_t)t * 128 + j + 64] = o2;
        }
    }
}

// ----------------------------------------------------------------
extern "C" void kernel_launch(void* const* d_in, const int* in_sizes, int n_in,
                              void* d_out, int out_size, void* d_ws, size_t ws_size,
                              hipStream_t stream)
{
    float* ws = (float*)d_ws;
    Params P;
    P.su8 = (const unsigned char*)d_in[2];
    P.si32 = (const int*)d_in[2];
    P.x   = (const float*)d_in[0];
    P.st0 = (const float*)d_in[1];
    P.a   = (const float*)d_in[3];
    P.b   = (const float*)d_in[4];
    P.W1  = (const float*)d_in[5];  P.b1  = (const float*)d_in[6];
    P.W2  = (const float*)d_in[7];  P.b2  = (const float*)d_in[8];
    P.Wgi = (const float*)d_in[9];  P.bgi = (const float*)d_in[10];
    P.Wp  = (const float*)d_in[11]; P.bp  = (const float*)d_in[12];
    P.Wz  = (const float*)d_in[13]; P.bz  = (const float*)d_in[14];
    P.Wgo = (const float*)d_in[15]; P.bgo = (const float*)d_in[16];
    P.Wsk = (const float*)d_in[17]; P.bsk = (const float*)d_in[18];
    P.W3  = (const float*)d_in[19]; P.b3  = (const float*)d_in[20];
    P.W4  = (const float*)d_in[21]; P.b4  = (const float*)d_in[22];
    P.gated = ws + OFF_GATED;
    P.go    = ws + OFF_GO;
    P.sk    = ws + OFF_SKIP;
    P.part  = ws + OFF_PART;
    P.flags = (int*)(ws + OFF_FLAGS);
    P.chs   = (int*)(ws + OFF_CHS);
    P.wzt   = (unsigned short*)(ws + OFF_WZT);
    P.carryB = (float2*)(ws + OFF_SCR);
    P.cinArr = (float2*)(ws + OFF_SCR + 524288);
    P.out   = (float*)d_out;
    P.arr   = (int*)(ws + OFF_BAR);
    P.gow   = (int*)(ws + OFF_BAR) + NBLK * 32;

    hipMemsetAsync((int*)(ws + OFF_BAR), 0, (NBLK * 32 + 32) * sizeof(int), stream);
    hipLaunchKernelGGL(k_mega, dim3(NBLK), dim3(512), 0, stream, P);
}

// Round 13
// 115.223 us; speedup vs baseline: 1.5105x; 1.2698x over previous
//
#include <hip/hip_runtime.h>
#include <math.h>

#define T_LEN 4096
#define D_IN 128
#define KDIM 4096   // TR*CTX
#define K2   8192   // re+im

// ws float offsets
#define OFF_GATED 0u
#define OFF_GO    262144u
#define OFF_SKIP  524288u
#define OFF_PART  786432u          // 16 * 262144 partials
#define OFF_FLAGS 4980736u         // 4096 ints
#define OFF_CHS   4984832u         // 64 ints
#define OFF_WZT   4984896u         // 524288 bf16 = 262144 float slots
#define OFF_SCR   5247040u         // carryB 524288 floats

typedef __attribute__((ext_vector_type(8))) short short8v;
typedef __attribute__((ext_vector_type(4))) float float4v;

__device__ __forceinline__ float sigm(float x){ return 1.f/(1.f+expf(-x)); }
__device__ __forceinline__ unsigned short f2bf(float x){
    unsigned int u = __float_as_uint(x);
    return (unsigned short)((u + 0x7FFFu + ((u >> 16) & 1u)) >> 16);
}
__device__ __forceinline__ float wsum(float v) {
#pragma unroll
    for (int o = 32; o; o >>= 1) v += __shfl_xor(v, o, 64);
    return v;
}

// ---------------------------------------------------------------- prep: flags | wzt | mlp  (role by blockIdx)
__global__ __launch_bounds__(512) void k_prep(
    const unsigned char* __restrict__ su8, const int* __restrict__ si32,
    int* __restrict__ flags, int* __restrict__ chunkStart,
    const float* __restrict__ Wz, unsigned short* __restrict__ wzt,
    const float* __restrict__ x,
    const float* __restrict__ W1, const float* __restrict__ b1,
    const float* __restrict__ W2, const float* __restrict__ b2,
    const float* __restrict__ Wgi, const float* __restrict__ bgi,
    const float* __restrict__ Wp,  const float* __restrict__ bp,
    const float* __restrict__ Wgo, const float* __restrict__ bgo,
    const float* __restrict__ Wsk, const float* __restrict__ bsk,
    float* __restrict__ gated, float* __restrict__ go, float* __restrict__ sk)
{
    const int bx = blockIdx.x;
    const int tid = threadIdx.x;

    if (bx == 0) {
        __shared__ int cnt;
        if (tid == 0) cnt = 0;
        __syncthreads();
        int local = 0;
        for (int i = tid; i < 4096; i += 512)
            if (i & 3) local += su8[i];
        if (local) atomicAdd(&cnt, local);
        __syncthreads();
        if (cnt > 0) { for (int i = tid; i < 4096; i += 512) flags[i] = su8[i] ? 1 : 0; }
        else         { for (int i = tid; i < 4096; i += 512) flags[i] = si32[i] ? 1 : 0; }
        __syncthreads();
        if (tid < 64) {
            int any = 0;
#pragma unroll 8
            for (int j = 0; j < 64; ++j) any |= flags[tid * 64 + j];
            chunkStart[tid] = any;
        }
        return;
    }
    if (bx <= 64) {   // wzt[j][k] = bf16(Wz[k][j])
        int idx = ((bx - 1) * 512 + tid) * 16;
        int j = idx >> 13, k0 = idx & 8191;
#pragma unroll
        for (int e = 0; e < 16; ++e) {
            int k = k0 + e;
            wzt[(size_t)j * K2 + k] = f2bf(Wz[(size_t)k * 64 + j]);
        }
        return;
    }

    // mlp: 8 rows per block, weights-in-VGPR
    __shared__ float xs[8][128];
    __shared__ float hs[8][64];
    __shared__ float h2s[8][128];
    __shared__ float tmp[8][4][64];
    const int t0 = (bx - 65) * 8;

    if (tid < 256) {
        int r = tid >> 5, kq = (tid & 31) << 2;
        *(float4*)&xs[r][kq] = *(const float4*)&x[(size_t)(t0 + r) * D_IN + kq];
    }

    const int j1 = tid >> 3, ks1 = tid & 7;
    float wr1[16];
#pragma unroll
    for (int kk = 0; kk < 16; ++kk) wr1[kk] = W1[(size_t)(ks1 * 16 + kk) * 64 + j1];
    const float bias1 = b1[j1];
    __syncthreads();
#pragma unroll
    for (int r = 0; r < 8; ++r) {
        float p = 0.f;
#pragma unroll
        for (int kq = 0; kq < 4; ++kq) {
            float4 xv = *(const float4*)&xs[r][ks1 * 16 + kq * 4];
            p += xv.x*wr1[kq*4] + xv.y*wr1[kq*4+1] + xv.z*wr1[kq*4+2] + xv.w*wr1[kq*4+3];
        }
        p += __shfl_xor(p, 1, 64); p += __shfl_xor(p, 2, 64); p += __shfl_xor(p, 4, 64);
        if (ks1 == 0) hs[r][j1] = fmaxf(p + bias1, 0.f);
    }
    __syncthreads();

    const int j2 = tid >> 2, ks2 = tid & 3;
    float wr2[16];
#pragma unroll
    for (int kk = 0; kk < 16; ++kk) wr2[kk] = W2[(size_t)(ks2 * 16 + kk) * 128 + j2];
    const float bias2 = b2[j2];
#pragma unroll
    for (int r = 0; r < 8; ++r) {
        float p = 0.f;
#pragma unroll
        for (int kq = 0; kq < 4; ++kq) {
            float4 hv = *(const float4*)&hs[r][ks2 * 16 + kq * 4];
            p += hv.x*wr2[kq*4] + hv.y*wr2[kq*4+1] + hv.z*wr2[kq*4+2] + hv.w*wr2[kq*4+3];
        }
        p += __shfl_xor(p, 1, 64); p += __shfl_xor(p, 2, 64);
        if (ks2 == 0) h2s[r][j2] = p + bias2;
    }
    __syncthreads();

    const int mat = tid >> 7, jj = (tid & 127) >> 1, kh = tid & 1;
    const float* Wm = (mat == 0) ? Wgi : (mat == 1) ? Wp : (mat == 2) ? Wgo : Wsk;
    float wgr[64];
#pragma unroll
    for (int kk = 0; kk < 64; ++kk) wgr[kk] = Wm[(size_t)(kh * 64 + kk) * 64 + jj];
#pragma unroll
    for (int r = 0; r < 8; ++r) {
        float p = 0.f;
#pragma unroll
        for (int kq = 0; kq < 16; ++kq) {
            float4 hv = *(const float4*)&h2s[r][kh * 64 + kq * 4];
            p += hv.x*wgr[kq*4] + hv.y*wgr[kq*4+1] + hv.z*wgr[kq*4+2] + hv.w*wgr[kq*4+3];
        }
        p += __shfl_xor(p, 1, 64);
        if (kh == 0) tmp[r][mat][jj] = p;
    }
    __syncthreads();

    {
        int r = tid >> 6, j = tid & 63;
        int t = t0 + r;
        float gi = sigm(tmp[r][0][j] + bgi[j]);
        float pr = sigm(tmp[r][1][j] + bp[j]);
        float g  = sigm(tmp[r][2][j] + bgo[j]);
        float s  = tmp[r][3][j] + bsk[j];
        gated[t * 64 + j] = gi * pr;
        go[t * 64 + j]    = g;
        sk[t * 64 + j]    = s;
    }
}

// ---------------------------------------------------------------- scan A: per-chunk local carries (8 chains/block)
__global__ __launch_bounds__(512) void k_scanA(
    const float* __restrict__ gated, const int* __restrict__ flags,
    const float* __restrict__ a, const float* __restrict__ b,
    float2* __restrict__ carryB)
{
    const int p = threadIdx.x >> 6, c = threadIdx.x & 63;
    const int pair = blockIdx.x * 8 + p;
    const int ch = pair & 63, m = pair >> 6;
    const int t0 = ch * 64;

    const double ea = exp(-fabs((double)a[m]));
    const double bb = (double)b[c];
    const double lre = ea * cos(bb), lim = ea * sin(bb);
    float gv = gated[(size_t)(t0 + c) * 64 + m];
    unsigned long long fmask = __ballot(flags[t0 + c] != 0);
    double sre = 0.0, sim = 0.0;
#pragma unroll 8
    for (int j = 0; j < 64; ++j) {
        double g = (double)__shfl(gv, j, 64);
        if ((fmask >> j) & 1) { sre = g; sim = 0.0; }
        else {
            double nr = fma(sre, lre, fma(-sim, lim, g));
            double ni = fma(sre, lim, sim * lre);
            sre = nr; sim = ni;
        }
    }
    carryB[(size_t)ch * KDIM + m * 64 + c] = make_float2((float)sre, (float)sim);
}

// ---------------------------------------------------------------- scanBZq: carry-prefix + seeded scan -> LDS -> MFMA
// grid: 1024 blocks = (ch 0..63) x (mg 0..15); 256 thr = 4 waves (ml) x 64 lanes (c)
__global__ __launch_bounds__(256) void k_scanBZq(
    const float* __restrict__ gated, const int* __restrict__ flags,
    const int* __restrict__ chs,
    const float* __restrict__ a, const float* __restrict__ b,
    const float* __restrict__ st0,
    const float2* __restrict__ carryB,
    const unsigned short* __restrict__ wzt,
    float* __restrict__ part,
    float* __restrict__ out)
{
    const int tid = threadIdx.x;
    const int ml = tid >> 6, c = tid & 63;       // ml = wave index
    const int ch = blockIdx.x & 63, mg = blockIdx.x >> 6;
    const int m = mg * 4 + ml;
    const int t0 = ch * 64;
    __shared__ unsigned short st[64 * 512];      // 64KB, swizzled chunks of 8 elems

    // per-chain lambda
    const double ea = exp(-fabs((double)a[m]));
    const double bb = (double)b[c];
    const double lre = ea * cos(bb), lim = ea * sin(bb);

    // ---- carry prefix: cin for chunk ch (f64, f32 carry inputs — same math as old scanC)
    unsigned long long cmask = __ballot(chs[c] != 0);
    const double ea64 = exp(-64.0 * fabs((double)a[m]));
    const double l64re = ea64 * cos(64.0 * bb), l64im = ea64 * sin(64.0 * bb);
    double cre = (double)st0[(m * 64 + c) * 2];
    double cim = (double)st0[(m * 64 + c) * 2 + 1];
    for (int chp = 0; chp < ch; ++chp) {
        float2 B = carryB[(size_t)chp * KDIM + m * 64 + c];
        if ((cmask >> chp) & 1) { cre = (double)B.x; cim = (double)B.y; }
        else {
            double nr = fma(cre, l64re, fma(-cim, l64im, (double)B.x));
            double ni = fma(cre, l64im, fma(cim, l64re, (double)B.y));
            cre = nr; cim = ni;
        }
    }

    // ---- seeded scan (f64 cin), write bf16 tile (XOR-swizzled)
    float gv = gated[(size_t)(t0 + c) * 64 + m];
    unsigned long long fmask = __ballot(flags[t0 + c] != 0);
    double sre = cre, sim = cim;
    const int e0 = ml * 128 + c, e1 = e0 + 64;
#pragma unroll 4
    for (int j = 0; j < 64; ++j) {
        double g = (double)__shfl(gv, j, 64);
        if ((fmask >> j) & 1) { sre = g; sim = 0.0; }
        else {
            double nr = fma(sre, lre, fma(-sim, lim, g));
            double ni = fma(sre, lim, sim * lre);
            sre = nr; sim = ni;
        }
        const int sx = (j & 7) << 3;
        st[j * 512 + (e0 ^ sx)] = f2bf((float)sre);
        st[j * 512 + (e1 ^ sx)] = f2bf((float)sim);
    }
    if (ch == 63) {   // t = 4095: final state, planar f32
        out[524288 + m * 64 + c]        = (float)sre;
        out[524288 + 4096 + m * 64 + c] = (float)sim;
    }

    // ---- B fragments (L2-hot), then MFMA against the tile
    const int l = c;
    const int jrow = ml * 16 + (l & 15);
    short8v bfr[16];
#pragma unroll
    for (int ks = 0; ks < 16; ++ks)
        bfr[ks] = *(const short8v*)&wzt[(size_t)jrow * K2 + mg * 512 + (ks * 4 + (l >> 4)) * 8];

    __syncthreads();

    float4v acc[4];
#pragma unroll
    for (int i = 0; i < 4; ++i) acc[i] = (float4v){0.f, 0.f, 0.f, 0.f};
#pragma unroll
    for (int ks = 0; ks < 16; ++ks) {
#pragma unroll
        for (int mt = 0; mt < 4; ++mt) {
            const int row = mt * 16 + (l & 15);
            const int rchunk = (ks * 4 + (l >> 4)) ^ (row & 7);
            short8v af = *(const short8v*)&st[row * 512 + rchunk * 8];
            acc[mt] = __builtin_amdgcn_mfma_f32_16x16x32_bf16(af, bfr[ks], acc[mt], 0, 0, 0);
        }
    }

    // C/D: t-row = mt*16 + (lane>>4)*4 + r; j-col = ml*16 + (lane&15)
    float* pp = part + (size_t)mg * 262144;
    const int jcol = ml * 16 + (l & 15);
#pragma unroll
    for (int mt = 0; mt < 4; ++mt) {
        const int trow = t0 + mt * 16 + (l >> 4) * 4;
#pragma unroll
        for (int r = 0; r < 4; ++r)
            pp[(size_t)(trow + r) * 64 + jcol] = acc[mt][r];
    }
}

// ---------------------------------------------------------------- epilogue
__global__ __launch_bounds__(256) void k_epi(
    const float* __restrict__ part, const float* __restrict__ bz,
    const float* __restrict__ go, const float* __restrict__ sk,
    const float* __restrict__ W3, const float* __restrict__ b3,
    const float* __restrict__ W4, const float* __restrict__ b4,
    float* __restrict__ out)
{
    __shared__ float ob[4][64], hb[4][64];
    const int w = threadIdx.x >> 6, j = threadIdx.x & 63;
    const int t = blockIdx.x * 4 + w;
    float z = bz[j];
#pragma unroll
    for (int p = 0; p < 16; ++p) z += part[(size_t)p * 262144 + t * 64 + j];
    float g = go[t * 64 + j];
    float y = z * g;
    float mu = wsum(y) * 0.015625f;
    float d = y - mu;
    float var = wsum(d * d) * 0.015625f;
    float o = d * (1.f / sqrtf(var + 1e-6f)) + sk[t * 64 + j] * (1.f - g);
    ob[w][j] = o;
    __syncthreads();
    float acc = b3[j];
#pragma unroll 8
    for (int k = 0; k < 64; ++k) acc += ob[w][k] * W3[k * 64 + j];
    hb[w][j] = fmaxf(acc, 0.f);
    __syncthreads();
    float o1 = b4[j], o2 = b4[j + 64];
#pragma unroll 8
    for (int k = 0; k < 64; ++k) { float hv = hb[w][k]; o1 += hv * W4[k * 128 + j]; o2 += hv * W4[k * 128 + j + 64]; }
    out[(size_t)t * 128 + j] = o1;
    out[(size_t)t * 128 + j + 64] = o2;
}

// ----------------------------------------------------------------
extern "C" void kernel_launch(void* const* d_in, const int* in_sizes, int n_in,
                              void* d_out, int out_size, void* d_ws, size_t ws_size,
                              hipStream_t stream)
{
    const float* x   = (const float*)d_in[0];
    const float* st0 = (const float*)d_in[1];
    const void*  start = d_in[2];
    const float* a  = (const float*)d_in[3];
    const float* b  = (const float*)d_in[4];
    const float* W1 = (const float*)d_in[5];  const float* b1 = (const float*)d_in[6];
    const float* W2 = (const float*)d_in[7];  const float* b2 = (const float*)d_in[8];
    const float* Wgi= (const float*)d_in[9];  const float* bgi= (const float*)d_in[10];
    const float* Wp = (const float*)d_in[11]; const float* bp = (const float*)d_in[12];
    const float* Wz = (const float*)d_in[13]; const float* bz = (const float*)d_in[14];
    const float* Wgo= (const float*)d_in[15]; const float* bgo= (const float*)d_in[16];
    const float* Wsk= (const float*)d_in[17]; const float* bsk= (const float*)d_in[18];
    const float* W3 = (const float*)d_in[19]; const float* b3 = (const float*)d_in[20];
    const float* W4 = (const float*)d_in[21]; const float* b4 = (const float*)d_in[22];

    float* ws    = (float*)d_ws;
    float* out   = (float*)d_out;
    float* gated = ws + OFF_GATED;
    float* go    = ws + OFF_GO;
    float* sk    = ws + OFF_SKIP;
    float* part  = ws + OFF_PART;
    int*   flags = (int*)(ws + OFF_FLAGS);
    int*   chs   = (int*)(ws + OFF_CHS);
    unsigned short* wzt = (unsigned short*)(ws + OFF_WZT);
    float2* carryB = (float2*)(ws + OFF_SCR);

    hipLaunchKernelGGL(k_prep, dim3(577), dim3(512), 0, stream,
                       (const unsigned char*)start, (const int*)start, flags, chs,
                       Wz, wzt, x, W1, b1, W2, b2, Wgi, bgi, Wp, bp,
                       Wgo, bgo, Wsk, bsk, gated, go, sk);
    hipLaunchKernelGGL(k_scanA, dim3(512), dim3(512), 0, stream,
                       gated, flags, a, b, carryB);
    hipLaunchKernelGGL(k_scanBZq, dim3(1024), dim3(256), 0, stream,
                       gated, flags, chs, a, b, st0, carryB, wzt, part, out);
    hipLaunchKernelGGL(k_epi, dim3(1024), dim3(256), 0, stream,
                       part, bz, go, sk, W3, b3, W4, b4, out);
}

// Round 14
// 88.318 us; speedup vs baseline: 1.9707x; 1.3046x over previous
//
#include <hip/hip_runtime.h>
#include <math.h>

#define T_LEN 4096
#define D_IN 128
#define KDIM 4096   // TR*CTX
#define K2   8192   // re+im

// ws float offsets
#define OFF_GATED 0u
#define OFF_GO    262144u
#define OFF_SKIP  524288u
#define OFF_PART  786432u          // 16 * 262144 partials
#define OFF_FLAGS 4980736u         // 4096 ints
#define OFF_CHS   4984832u         // 64 ints
#define OFF_WZT   4984896u         // 524288 bf16 = 262144 float slots
#define OFF_SCR   5247040u         // carryB 524288 floats

typedef __attribute__((ext_vector_type(8))) short short8v;
typedef __attribute__((ext_vector_type(4))) float float4v;

__device__ __forceinline__ float sigm(float x){ return 1.f/(1.f+expf(-x)); }
__device__ __forceinline__ unsigned short f2bf(float x){
    unsigned int u = __float_as_uint(x);
    return (unsigned short)((u + 0x7FFFu + ((u >> 16) & 1u)) >> 16);
}
__device__ __forceinline__ float wsum(float v) {
#pragma unroll
    for (int o = 32; o; o >>= 1) v += __shfl_xor(v, o, 64);
    return v;
}

// ---------------------------------------------------------------- prep: flags | wzt | mlp  (role by blockIdx)
__global__ __launch_bounds__(512) void k_prep(
    const unsigned char* __restrict__ su8, const int* __restrict__ si32,
    int* __restrict__ flags, int* __restrict__ chunkStart,
    const float* __restrict__ Wz, unsigned short* __restrict__ wzt,
    const float* __restrict__ x,
    const float* __restrict__ W1, const float* __restrict__ b1,
    const float* __restrict__ W2, const float* __restrict__ b2,
    const float* __restrict__ Wgi, const float* __restrict__ bgi,
    const float* __restrict__ Wp,  const float* __restrict__ bp,
    const float* __restrict__ Wgo, const float* __restrict__ bgo,
    const float* __restrict__ Wsk, const float* __restrict__ bsk,
    float* __restrict__ gated, float* __restrict__ go, float* __restrict__ sk)
{
    const int bx = blockIdx.x;
    const int tid = threadIdx.x;

    if (bx == 0) {
        __shared__ int cnt;
        if (tid == 0) cnt = 0;
        __syncthreads();
        int local = 0;
        for (int i = tid; i < 4096; i += 512)
            if (i & 3) local += su8[i];
        if (local) atomicAdd(&cnt, local);
        __syncthreads();
        if (cnt > 0) { for (int i = tid; i < 4096; i += 512) flags[i] = su8[i] ? 1 : 0; }
        else         { for (int i = tid; i < 4096; i += 512) flags[i] = si32[i] ? 1 : 0; }
        __syncthreads();
        if (tid < 64) {
            int any = 0;
#pragma unroll 8
            for (int j = 0; j < 64; ++j) any |= flags[tid * 64 + j];
            chunkStart[tid] = any;
        }
        return;
    }
    if (bx <= 64) {   // wzt[j][k] = bf16(Wz[k][j])
        int idx = ((bx - 1) * 512 + tid) * 16;
        int j = idx >> 13, k0 = idx & 8191;
#pragma unroll
        for (int e = 0; e < 16; ++e) {
            int k = k0 + e;
            wzt[(size_t)j * K2 + k] = f2bf(Wz[(size_t)k * 64 + j]);
        }
        return;
    }

    // mlp: 8 rows per block, weights-in-VGPR
    __shared__ float xs[8][128];
    __shared__ float hs[8][64];
    __shared__ float h2s[8][128];
    __shared__ float tmp[8][4][64];
    const int t0 = (bx - 65) * 8;

    if (tid < 256) {
        int r = tid >> 5, kq = (tid & 31) << 2;
        *(float4*)&xs[r][kq] = *(const float4*)&x[(size_t)(t0 + r) * D_IN + kq];
    }

    const int j1 = tid >> 3, ks1 = tid & 7;
    float wr1[16];
#pragma unroll
    for (int kk = 0; kk < 16; ++kk) wr1[kk] = W1[(size_t)(ks1 * 16 + kk) * 64 + j1];
    const float bias1 = b1[j1];
    __syncthreads();
#pragma unroll
    for (int r = 0; r < 8; ++r) {
        float p = 0.f;
#pragma unroll
        for (int kq = 0; kq < 4; ++kq) {
            float4 xv = *(const float4*)&xs[r][ks1 * 16 + kq * 4];
            p += xv.x*wr1[kq*4] + xv.y*wr1[kq*4+1] + xv.z*wr1[kq*4+2] + xv.w*wr1[kq*4+3];
        }
        p += __shfl_xor(p, 1, 64); p += __shfl_xor(p, 2, 64); p += __shfl_xor(p, 4, 64);
        if (ks1 == 0) hs[r][j1] = fmaxf(p + bias1, 0.f);
    }
    __syncthreads();

    const int j2 = tid >> 2, ks2 = tid & 3;
    float wr2[16];
#pragma unroll
    for (int kk = 0; kk < 16; ++kk) wr2[kk] = W2[(size_t)(ks2 * 16 + kk) * 128 + j2];
    const float bias2 = b2[j2];
#pragma unroll
    for (int r = 0; r < 8; ++r) {
        float p = 0.f;
#pragma unroll
        for (int kq = 0; kq < 4; ++kq) {
            float4 hv = *(const float4*)&hs[r][ks2 * 16 + kq * 4];
            p += hv.x*wr2[kq*4] + hv.y*wr2[kq*4+1] + hv.z*wr2[kq*4+2] + hv.w*wr2[kq*4+3];
        }
        p += __shfl_xor(p, 1, 64); p += __shfl_xor(p, 2, 64);
        if (ks2 == 0) h2s[r][j2] = p + bias2;
    }
    __syncthreads();

    const int mat = tid >> 7, jj = (tid & 127) >> 1, kh = tid & 1;
    const float* Wm = (mat == 0) ? Wgi : (mat == 1) ? Wp : (mat == 2) ? Wgo : Wsk;
    float wgr[64];
#pragma unroll
    for (int kk = 0; kk < 64; ++kk) wgr[kk] = Wm[(size_t)(kh * 64 + kk) * 64 + jj];
#pragma unroll
    for (int r = 0; r < 8; ++r) {
        float p = 0.f;
#pragma unroll
        for (int kq = 0; kq < 16; ++kq) {
            float4 hv = *(const float4*)&h2s[r][kh * 64 + kq * 4];
            p += hv.x*wgr[kq*4] + hv.y*wgr[kq*4+1] + hv.z*wgr[kq*4+2] + hv.w*wgr[kq*4+3];
        }
        p += __shfl_xor(p, 1, 64);
        if (kh == 0) tmp[r][mat][jj] = p;
    }
    __syncthreads();

    {
        int r = tid >> 6, j = tid & 63;
        int t = t0 + r;
        float gi = sigm(tmp[r][0][j] + bgi[j]);
        float pr = sigm(tmp[r][1][j] + bp[j]);
        float g  = sigm(tmp[r][2][j] + bgo[j]);
        float s  = tmp[r][3][j] + bsk[j];
        gated[t * 64 + j] = gi * pr;
        go[t * 64 + j]    = g;
        sk[t * 64 + j]    = s;
    }
}

// ---------------------------------------------------------------- scan A: per-chunk local carries (8 chains/block)
__global__ __launch_bounds__(512) void k_scanA(
    const float* __restrict__ gated, const int* __restrict__ flags,
    const float* __restrict__ a, const float* __restrict__ b,
    float2* __restrict__ carryB)
{
    const int p = threadIdx.x >> 6, c = threadIdx.x & 63;
    const int pair = blockIdx.x * 8 + p;
    const int ch = pair & 63, m = pair >> 6;
    const int t0 = ch * 64;

    const double ea = exp(-fabs((double)a[m]));
    const double bb = (double)b[c];
    const double lre = ea * cos(bb), lim = ea * sin(bb);
    float gv = gated[(size_t)(t0 + c) * 64 + m];
    unsigned long long fmask = __ballot(flags[t0 + c] != 0);
    double sre = 0.0, sim = 0.0;
#pragma unroll 8
    for (int j = 0; j < 64; ++j) {
        double g = (double)__shfl(gv, j, 64);
        if ((fmask >> j) & 1) { sre = g; sim = 0.0; }
        else {
            double nr = fma(sre, lre, fma(-sim, lim, g));
            double ni = fma(sre, lim, sim * lre);
            sre = nr; sim = ni;
        }
    }
    carryB[(size_t)ch * KDIM + m * 64 + c] = make_float2((float)sre, (float)sim);
}

// ---------------------------------------------------------------- scanBZq: carry-prefix + seeded scan -> LDS -> MFMA
// grid: 1024 blocks = (ch 0..63) x (mg 0..15); 256 thr = 4 waves (ml) x 64 lanes (c)
__global__ __launch_bounds__(256) void k_scanBZq(
    const float* __restrict__ gated, const int* __restrict__ flags,
    const int* __restrict__ chs,
    const float* __restrict__ a, const float* __restrict__ b,
    const float* __restrict__ st0,
    const float2* __restrict__ carryB,
    const unsigned short* __restrict__ wzt,
    float* __restrict__ part,
    float* __restrict__ out)
{
    const int tid = threadIdx.x;
    const int ml = tid >> 6, c = tid & 63;       // ml = wave index
    const int ch = blockIdx.x & 63, mg = blockIdx.x >> 6;
    const int m = mg * 4 + ml;
    const int t0 = ch * 64;
    __shared__ unsigned short st[64 * 512];      // 64KB, swizzled chunks of 8 elems

    // per-chain lambda
    const double ea = exp(-fabs((double)a[m]));
    const double bb = (double)b[c];
    const double lre = ea * cos(bb), lim = ea * sin(bb);

    // ---- carry prefix for chunk ch: load ALL 64 carries up-front (independent
    // loads -> one memory latency), then fully-unrolled combine predicated on
    // the wave-uniform chp<ch (same math/order as before -> bitwise identical).
    unsigned long long cmask = __ballot(chs[c] != 0);
    const double ea64 = exp(-64.0 * fabs((double)a[m]));
    const double l64re = ea64 * cos(64.0 * bb), l64im = ea64 * sin(64.0 * bb);
    double cre = (double)st0[(m * 64 + c) * 2];
    double cim = (double)st0[(m * 64 + c) * 2 + 1];
    {
        float2 Bv[64];
#pragma unroll
        for (int chp = 0; chp < 64; ++chp)
            Bv[chp] = carryB[(size_t)chp * KDIM + m * 64 + c];
#pragma unroll
        for (int chp = 0; chp < 63; ++chp) {
            if (chp < ch) {   // wave-uniform scalar branch
                if ((cmask >> chp) & 1) { cre = (double)Bv[chp].x; cim = (double)Bv[chp].y; }
                else {
                    double nr = fma(cre, l64re, fma(-cim, l64im, (double)Bv[chp].x));
                    double ni = fma(cre, l64im, fma(cim, l64re, (double)Bv[chp].y));
                    cre = nr; cim = ni;
                }
            }
        }
    }

    // ---- seeded scan (f64 cin), write bf16 tile (XOR-swizzled)
    float gv = gated[(size_t)(t0 + c) * 64 + m];
    unsigned long long fmask = __ballot(flags[t0 + c] != 0);
    double sre = cre, sim = cim;
    const int e0 = ml * 128 + c, e1 = e0 + 64;
#pragma unroll 4
    for (int j = 0; j < 64; ++j) {
        double g = (double)__shfl(gv, j, 64);
        if ((fmask >> j) & 1) { sre = g; sim = 0.0; }
        else {
            double nr = fma(sre, lre, fma(-sim, lim, g));
            double ni = fma(sre, lim, sim * lre);
            sre = nr; sim = ni;
        }
        const int sx = (j & 7) << 3;
        st[j * 512 + (e0 ^ sx)] = f2bf((float)sre);
        st[j * 512 + (e1 ^ sx)] = f2bf((float)sim);
    }
    if (ch == 63) {   // t = 4095: final state, planar f32
        out[524288 + m * 64 + c]        = (float)sre;
        out[524288 + 4096 + m * 64 + c] = (float)sim;
    }

    // ---- B fragments (L2-hot), then MFMA against the tile
    const int l = c;
    const int jrow = ml * 16 + (l & 15);
    short8v bfr[16];
#pragma unroll
    for (int ks = 0; ks < 16; ++ks)
        bfr[ks] = *(const short8v*)&wzt[(size_t)jrow * K2 + mg * 512 + (ks * 4 + (l >> 4)) * 8];

    __syncthreads();

    float4v acc[4];
#pragma unroll
    for (int i = 0; i < 4; ++i) acc[i] = (float4v){0.f, 0.f, 0.f, 0.f};
#pragma unroll
    for (int ks = 0; ks < 16; ++ks) {
#pragma unroll
        for (int mt = 0; mt < 4; ++mt) {
            const int row = mt * 16 + (l & 15);
            const int rchunk = (ks * 4 + (l >> 4)) ^ (row & 7);
            short8v af = *(const short8v*)&st[row * 512 + rchunk * 8];
            acc[mt] = __builtin_amdgcn_mfma_f32_16x16x32_bf16(af, bfr[ks], acc[mt], 0, 0, 0);
        }
    }

    // C/D: t-row = mt*16 + (lane>>4)*4 + r; j-col = ml*16 + (lane&15)
    float* pp = part + (size_t)mg * 262144;
    const int jcol = ml * 16 + (l & 15);
#pragma unroll
    for (int mt = 0; mt < 4; ++mt) {
        const int trow = t0 + mt * 16 + (l >> 4) * 4;
#pragma unroll
        for (int r = 0; r < 4; ++r)
            pp[(size_t)(trow + r) * 64 + jcol] = acc[mt][r];
    }
}

// ---------------------------------------------------------------- epilogue
__global__ __launch_bounds__(256) void k_epi(
    const float* __restrict__ part, const float* __restrict__ bz,
    const float* __restrict__ go, const float* __restrict__ sk,
    const float* __restrict__ W3, const float* __restrict__ b3,
    const float* __restrict__ W4, const float* __restrict__ b4,
    float* __restrict__ out)
{
    __shared__ float ob[4][64], hb[4][64];
    const int w = threadIdx.x >> 6, j = threadIdx.x & 63;
    const int t = blockIdx.x * 4 + w;
    float z = bz[j];
#pragma unroll
    for (int p = 0; p < 16; ++p) z += part[(size_t)p * 262144 + t * 64 + j];
    float g = go[t * 64 + j];
    float y = z * g;
    float mu = wsum(y) * 0.015625f;
    float d = y - mu;
    float var = wsum(d * d) * 0.015625f;
    float o = d * (1.f / sqrtf(var + 1e-6f)) + sk[t * 64 + j] * (1.f - g);
    ob[w][j] = o;
    __syncthreads();
    float acc = b3[j];
#pragma unroll 8
    for (int k = 0; k < 64; ++k) acc += ob[w][k] * W3[k * 64 + j];
    hb[w][j] = fmaxf(acc, 0.f);
    __syncthreads();
    float o1 = b4[j], o2 = b4[j + 64];
#pragma unroll 8
    for (int k = 0; k < 64; ++k) { float hv = hb[w][k]; o1 += hv * W4[k * 128 + j]; o2 += hv * W4[k * 128 + j + 64]; }
    out[(size_t)t * 128 + j] = o1;
    out[(size_t)t * 128 + j + 64] = o2;
}

// ----------------------------------------------------------------
extern "C" void kernel_launch(void* const* d_in, const int* in_sizes, int n_in,
                              void* d_out, int out_size, void* d_ws, size_t ws_size,
                              hipStream_t stream)
{
    const float* x   = (const float*)d_in[0];
    const float* st0 = (const float*)d_in[1];
    const void*  start = d_in[2];
    const float* a  = (const float*)d_in[3];
    const float* b  = (const float*)d_in[4];
    const float* W1 = (const float*)d_in[5];  const float* b1 = (const float*)d_in[6];
    const float* W2 = (const float*)d_in[7];  const float* b2 = (const float*)d_in[8];
    const float* Wgi= (const float*)d_in[9];  const float* bgi= (const float*)d_in[10];
    const float* Wp = (const float*)d_in[11]; const float* bp = (const float*)d_in[12];
    const float* Wz = (const float*)d_in[13]; const float* bz = (const float*)d_in[14];
    const float* Wgo= (const float*)d_in[15]; const float* bgo= (const float*)d_in[16];
    const float* Wsk= (const float*)d_in[17]; const float* bsk= (const float*)d_in[18];
    const float* W3 = (const float*)d_in[19]; const float* b3 = (const float*)d_in[20];
    const float* W4 = (const float*)d_in[21]; const float* b4 = (const float*)d_in[22];

    float* ws    = (float*)d_ws;
    float* out   = (float*)d_out;
    float* gated = ws + OFF_GATED;
    float* go    = ws + OFF_GO;
    float* sk    = ws + OFF_SKIP;
    float* part  = ws + OFF_PART;
    int*   flags = (int*)(ws + OFF_FLAGS);
    int*   chs   = (int*)(ws + OFF_CHS);
    unsigned short* wzt = (unsigned short*)(ws + OFF_WZT);
    float2* carryB = (float2*)(ws + OFF_SCR);

    hipLaunchKernelGGL(k_prep, dim3(577), dim3(512), 0, stream,
                       (const unsigned char*)start, (const int*)start, flags, chs,
                       Wz, wzt, x, W1, b1, W2, b2, Wgi, bgi, Wp, bp,
                       Wgo, bgo, Wsk, bsk, gated, go, sk);
    hipLaunchKernelGGL(k_scanA, dim3(512), dim3(512), 0, stream,
                       gated, flags, a, b, carryB);
    hipLaunchKernelGGL(k_scanBZq, dim3(1024), dim3(256), 0, stream,
                       gated, flags, chs, a, b, st0, carryB, wzt, part, out);
    hipLaunchKernelGGL(k_epi, dim3(1024), dim3(256), 0, stream,
                       part, bz, go, sk, W3, b3, W4, b4, out);
}

// Round 15
// 86.428 us; speedup vs baseline: 2.0138x; 1.0219x over previous
//
#include <hip/hip_runtime.h>
#include <math.h>

#define T_LEN 4096
#define D_IN 128
#define KDIM 4096   // TR*CTX
#define K2   8192   // re+im

// ws float offsets
#define OFF_GATED 0u
#define OFF_GO    262144u
#define OFF_SKIP  524288u
#define OFF_PART  786432u          // 16 * 262144 partials
#define OFF_FLAGS 4980736u         // 4096 ints
#define OFF_CHS   4984832u         // 64 ints
#define OFF_WZT   4984896u         // 524288 bf16 = 262144 float slots
#define OFF_SCR   5247040u         // carryB 524288 floats

typedef __attribute__((ext_vector_type(8))) short short8v;
typedef __attribute__((ext_vector_type(4))) float float4v;

__device__ __forceinline__ float sigm(float x){ return 1.f/(1.f+expf(-x)); }
__device__ __forceinline__ unsigned short f2bf(float x){
    unsigned int u = __float_as_uint(x);
    return (unsigned short)((u + 0x7FFFu + ((u >> 16) & 1u)) >> 16);
}
__device__ __forceinline__ float wsum(float v) {
#pragma unroll
    for (int o = 32; o; o >>= 1) v += __shfl_xor(v, o, 64);
    return v;
}

// ---------------------------------------------------------------- prep: flags | wzt | mlp  (role by blockIdx)
__global__ __launch_bounds__(512) void k_prep(
    const unsigned char* __restrict__ su8, const int* __restrict__ si32,
    int* __restrict__ flags, int* __restrict__ chunkStart,
    const float* __restrict__ Wz, unsigned short* __restrict__ wzt,
    const float* __restrict__ x,
    const float* __restrict__ W1, const float* __restrict__ b1,
    const float* __restrict__ W2, const float* __restrict__ b2,
    const float* __restrict__ Wgi, const float* __restrict__ bgi,
    const float* __restrict__ Wp,  const float* __restrict__ bp,
    const float* __restrict__ Wgo, const float* __restrict__ bgo,
    const float* __restrict__ Wsk, const float* __restrict__ bsk,
    float* __restrict__ gated, float* __restrict__ go, float* __restrict__ sk)
{
    const int bx = blockIdx.x;
    const int tid = threadIdx.x;

    if (bx == 0) {
        __shared__ int cnt;
        if (tid == 0) cnt = 0;
        __syncthreads();
        int local = 0;
        for (int i = tid; i < 4096; i += 512)
            if (i & 3) local += su8[i];
        if (local) atomicAdd(&cnt, local);
        __syncthreads();
        if (cnt > 0) { for (int i = tid; i < 4096; i += 512) flags[i] = su8[i] ? 1 : 0; }
        else         { for (int i = tid; i < 4096; i += 512) flags[i] = si32[i] ? 1 : 0; }
        __syncthreads();
        if (tid < 64) {
            int any = 0;
#pragma unroll 8
            for (int j = 0; j < 64; ++j) any |= flags[tid * 64 + j];
            chunkStart[tid] = any;
        }
        return;
    }
    if (bx <= 64) {   // wzt[j][k] = bf16(Wz[k][j])
        int idx = ((bx - 1) * 512 + tid) * 16;
        int j = idx >> 13, k0 = idx & 8191;
#pragma unroll
        for (int e = 0; e < 16; ++e) {
            int k = k0 + e;
            wzt[(size_t)j * K2 + k] = f2bf(Wz[(size_t)k * 64 + j]);
        }
        return;
    }

    // mlp: 8 rows per block, weights-in-VGPR
    __shared__ float xs[8][128];
    __shared__ float hs[8][64];
    __shared__ float h2s[8][128];
    __shared__ float tmp[8][4][64];
    const int t0 = (bx - 65) * 8;

    if (tid < 256) {
        int r = tid >> 5, kq = (tid & 31) << 2;
        *(float4*)&xs[r][kq] = *(const float4*)&x[(size_t)(t0 + r) * D_IN + kq];
    }

    const int j1 = tid >> 3, ks1 = tid & 7;
    float wr1[16];
#pragma unroll
    for (int kk = 0; kk < 16; ++kk) wr1[kk] = W1[(size_t)(ks1 * 16 + kk) * 64 + j1];
    const float bias1 = b1[j1];
    __syncthreads();
#pragma unroll
    for (int r = 0; r < 8; ++r) {
        float p = 0.f;
#pragma unroll
        for (int kq = 0; kq < 4; ++kq) {
            float4 xv = *(const float4*)&xs[r][ks1 * 16 + kq * 4];
            p += xv.x*wr1[kq*4] + xv.y*wr1[kq*4+1] + xv.z*wr1[kq*4+2] + xv.w*wr1[kq*4+3];
        }
        p += __shfl_xor(p, 1, 64); p += __shfl_xor(p, 2, 64); p += __shfl_xor(p, 4, 64);
        if (ks1 == 0) hs[r][j1] = fmaxf(p + bias1, 0.f);
    }
    __syncthreads();

    const int j2 = tid >> 2, ks2 = tid & 3;
    float wr2[16];
#pragma unroll
    for (int kk = 0; kk < 16; ++kk) wr2[kk] = W2[(size_t)(ks2 * 16 + kk) * 128 + j2];
    const float bias2 = b2[j2];
#pragma unroll
    for (int r = 0; r < 8; ++r) {
        float p = 0.f;
#pragma unroll
        for (int kq = 0; kq < 4; ++kq) {
            float4 hv = *(const float4*)&hs[r][ks2 * 16 + kq * 4];
            p += hv.x*wr2[kq*4] + hv.y*wr2[kq*4+1] + hv.z*wr2[kq*4+2] + hv.w*wr2[kq*4+3];
        }
        p += __shfl_xor(p, 1, 64); p += __shfl_xor(p, 2, 64);
        if (ks2 == 0) h2s[r][j2] = p + bias2;
    }
    __syncthreads();

    const int mat = tid >> 7, jj = (tid & 127) >> 1, kh = tid & 1;
    const float* Wm = (mat == 0) ? Wgi : (mat == 1) ? Wp : (mat == 2) ? Wgo : Wsk;
    float wgr[64];
#pragma unroll
    for (int kk = 0; kk < 64; ++kk) wgr[kk] = Wm[(size_t)(kh * 64 + kk) * 64 + jj];
#pragma unroll
    for (int r = 0; r < 8; ++r) {
        float p = 0.f;
#pragma unroll
        for (int kq = 0; kq < 16; ++kq) {
            float4 hv = *(const float4*)&h2s[r][kh * 64 + kq * 4];
            p += hv.x*wgr[kq*4] + hv.y*wgr[kq*4+1] + hv.z*wgr[kq*4+2] + hv.w*wgr[kq*4+3];
        }
        p += __shfl_xor(p, 1, 64);
        if (kh == 0) tmp[r][mat][jj] = p;
    }
    __syncthreads();

    {
        int r = tid >> 6, j = tid & 63;
        int t = t0 + r;
        float gi = sigm(tmp[r][0][j] + bgi[j]);
        float pr = sigm(tmp[r][1][j] + bp[j]);
        float g  = sigm(tmp[r][2][j] + bgo[j]);
        float s  = tmp[r][3][j] + bsk[j];
        gated[t * 64 + j] = gi * pr;
        go[t * 64 + j]    = g;
        sk[t * 64 + j]    = s;
    }
}

// ---------------------------------------------------------------- scan A: per-chunk local carries (8 chains/block)
__global__ __launch_bounds__(512) void k_scanA(
    const float* __restrict__ gated, const int* __restrict__ flags,
    const float* __restrict__ a, const float* __restrict__ b,
    float2* __restrict__ carryB)
{
    const int p = threadIdx.x >> 6, c = threadIdx.x & 63;
    const int pair = blockIdx.x * 8 + p;
    const int ch = pair & 63, m = pair >> 6;
    const int t0 = ch * 64;

    const double ea = exp(-fabs((double)a[m]));
    const double bb = (double)b[c];
    const double lre = ea * cos(bb), lim = ea * sin(bb);
    float gv = gated[(size_t)(t0 + c) * 64 + m];
    unsigned long long fmask = __ballot(flags[t0 + c] != 0);
    double sre = 0.0, sim = 0.0;
#pragma unroll 8
    for (int j = 0; j < 64; ++j) {
        double g = (double)__shfl(gv, j, 64);
        if ((fmask >> j) & 1) { sre = g; sim = 0.0; }
        else {
            double nr = fma(sre, lre, fma(-sim, lim, g));
            double ni = fma(sre, lim, sim * lre);
            sre = nr; sim = ni;
        }
    }
    carryB[(size_t)ch * KDIM + m * 64 + c] = make_float2((float)sre, (float)sim);
}

// ---------------------------------------------------------------- scanBZq: carry-prefix + seeded scan -> LDS -> MFMA
// grid: 1024 blocks = (ch 0..63) x (mg 0..15); 256 thr = 4 waves (ml) x 64 lanes (c)
__global__ __launch_bounds__(256) void k_scanBZq(
    const float* __restrict__ gated, const int* __restrict__ flags,
    const int* __restrict__ chs,
    const float* __restrict__ a, const float* __restrict__ b,
    const float* __restrict__ st0,
    const float2* __restrict__ carryB,
    const unsigned short* __restrict__ wzt,
    float* __restrict__ part,
    float* __restrict__ out)
{
    const int tid = threadIdx.x;
    const int ml = tid >> 6, c = tid & 63;       // ml = wave index
    const int ch = blockIdx.x & 63, mg = blockIdx.x >> 6;
    const int m = mg * 4 + ml;
    const int t0 = ch * 64;
    __shared__ unsigned short st[64 * 512];      // 64KB, swizzled chunks of 8 elems

    // per-chain lambda
    const double ea = exp(-fabs((double)a[m]));
    const double bb = (double)b[c];
    const double lre = ea * cos(bb), lim = ea * sin(bb);

    // ---- carry prefix for chunk ch: software-pipelined batches of 16
    // (two named 16-entry buffers -> no 128-reg live array -> no scratch spill;
    //  combine order identical to the sequential version -> bitwise same result)
    unsigned long long cmask = __ballot(chs[c] != 0);
    const double ea64 = exp(-64.0 * fabs((double)a[m]));
    const double l64re = ea64 * cos(64.0 * bb), l64im = ea64 * sin(64.0 * bb);
    double cre = (double)st0[(m * 64 + c) * 2];
    double cim = (double)st0[(m * 64 + c) * 2 + 1];
    {
        const float2* cbase = carryB + m * 64 + c;
        float2 BA[16], BB[16];
#define LOADB(dst, base)                                          \
        _Pragma("unroll")                                         \
        for (int q = 0; q < 16; ++q)                              \
            dst[q] = cbase[(size_t)((base) + q) * KDIM];
#define COMB(src, base)                                           \
        _Pragma("unroll")                                         \
        for (int q = 0; q < 16; ++q) {                            \
            int chp = (base) + q;                                 \
            if (chp < ch) {  /* wave-uniform scalar branch */     \
                if ((cmask >> chp) & 1) { cre = (double)src[q].x; cim = (double)src[q].y; } \
                else {                                            \
                    double nr = fma(cre, l64re, fma(-cim, l64im, (double)src[q].x)); \
                    double ni = fma(cre, l64im, fma(cim, l64re, (double)src[q].y)); \
                    cre = nr; cim = ni;                           \
                }                                                 \
            }                                                     \
        }
        if (ch > 0)  { LOADB(BA, 0) }
        if (ch > 16) { LOADB(BB, 16) }
        if (ch > 0)  { COMB(BA, 0) }
        if (ch > 32) { LOADB(BA, 32) }
        if (ch > 16) { COMB(BB, 16) }
        if (ch > 48) { LOADB(BB, 48) }
        if (ch > 32) { COMB(BA, 32) }
        if (ch > 48) { COMB(BB, 48) }
#undef LOADB
#undef COMB
    }

    // ---- seeded scan (f64 cin), write bf16 tile (XOR-swizzled)
    float gv = gated[(size_t)(t0 + c) * 64 + m];
    unsigned long long fmask = __ballot(flags[t0 + c] != 0);
    double sre = cre, sim = cim;
    const int e0 = ml * 128 + c, e1 = e0 + 64;
#pragma unroll 4
    for (int j = 0; j < 64; ++j) {
        double g = (double)__shfl(gv, j, 64);
        if ((fmask >> j) & 1) { sre = g; sim = 0.0; }
        else {
            double nr = fma(sre, lre, fma(-sim, lim, g));
            double ni = fma(sre, lim, sim * lre);
            sre = nr; sim = ni;
        }
        const int sx = (j & 7) << 3;
        st[j * 512 + (e0 ^ sx)] = f2bf((float)sre);
        st[j * 512 + (e1 ^ sx)] = f2bf((float)sim);
    }
    if (ch == 63) {   // t = 4095: final state, planar f32
        out[524288 + m * 64 + c]        = (float)sre;
        out[524288 + 4096 + m * 64 + c] = (float)sim;
    }

    // ---- B fragments (L2-hot), then MFMA against the tile
    const int l = c;
    const int jrow = ml * 16 + (l & 15);
    short8v bfr[16];
#pragma unroll
    for (int ks = 0; ks < 16; ++ks)
        bfr[ks] = *(const short8v*)&wzt[(size_t)jrow * K2 + mg * 512 + (ks * 4 + (l >> 4)) * 8];

    __syncthreads();

    float4v acc[4];
#pragma unroll
    for (int i = 0; i < 4; ++i) acc[i] = (float4v){0.f, 0.f, 0.f, 0.f};
#pragma unroll
    for (int ks = 0; ks < 16; ++ks) {
#pragma unroll
        for (int mt = 0; mt < 4; ++mt) {
            const int row = mt * 16 + (l & 15);
            const int rchunk = (ks * 4 + (l >> 4)) ^ (row & 7);
            short8v af = *(const short8v*)&st[row * 512 + rchunk * 8];
            acc[mt] = __builtin_amdgcn_mfma_f32_16x16x32_bf16(af, bfr[ks], acc[mt], 0, 0, 0);
        }
    }

    // C/D: t-row = mt*16 + (lane>>4)*4 + r; j-col = ml*16 + (lane&15)
    float* pp = part + (size_t)mg * 262144;
    const int jcol = ml * 16 + (l & 15);
#pragma unroll
    for (int mt = 0; mt < 4; ++mt) {
        const int trow = t0 + mt * 16 + (l >> 4) * 4;
#pragma unroll
        for (int r = 0; r < 4; ++r)
            pp[(size_t)(trow + r) * 64 + jcol] = acc[mt][r];
    }
}

// ---------------------------------------------------------------- epilogue
__global__ __launch_bounds__(256) void k_epi(
    const float* __restrict__ part, const float* __restrict__ bz,
    const float* __restrict__ go, const float* __restrict__ sk,
    const float* __restrict__ W3, const float* __restrict__ b3,
    const float* __restrict__ W4, const float* __restrict__ b4,
    float* __restrict__ out)
{
    __shared__ float ob[4][64], hb[4][64];
    const int w = threadIdx.x >> 6, j = threadIdx.x & 63;
    const int t = blockIdx.x * 4 + w;
    float z = bz[j];
#pragma unroll
    for (int p = 0; p < 16; ++p) z += part[(size_t)p * 262144 + t * 64 + j];
    float g = go[t * 64 + j];
    float y = z * g;
    float mu = wsum(y) * 0.015625f;
    float d = y - mu;
    float var = wsum(d * d) * 0.015625f;
    float o = d * (1.f / sqrtf(var + 1e-6f)) + sk[t * 64 + j] * (1.f - g);
    ob[w][j] = o;
    __syncthreads();
    float acc = b3[j];
#pragma unroll 8
    for (int k = 0; k < 64; ++k) acc += ob[w][k] * W3[k * 64 + j];
    hb[w][j] = fmaxf(acc, 0.f);
    __syncthreads();
    float o1 = b4[j], o2 = b4[j + 64];
#pragma unroll 8
    for (int k = 0; k < 64; ++k) { float hv = hb[w][k]; o1 += hv * W4[k * 128 + j]; o2 += hv * W4[k * 128 + j + 64]; }
    out[(size_t)t * 128 + j] = o1;
    out[(size_t)t * 128 + j + 64] = o2;
}

// ----------------------------------------------------------------
extern "C" void kernel_launch(void* const* d_in, const int* in_sizes, int n_in,
                              void* d_out, int out_size, void* d_ws, size_t ws_size,
                              hipStream_t stream)
{
    const float* x   = (const float*)d_in[0];
    const float* st0 = (const float*)d_in[1];
    const void*  start = d_in[2];
    const float* a  = (const float*)d_in[3];
    const float* b  = (const float*)d_in[4];
    const float* W1 = (const float*)d_in[5];  const float* b1 = (const float*)d_in[6];
    const float* W2 = (const float*)d_in[7];  const float* b2 = (const float*)d_in[8];
    const float* Wgi= (const float*)d_in[9];  const float* bgi= (const float*)d_in[10];
    const float* Wp = (const float*)d_in[11]; const float* bp = (const float*)d_in[12];
    const float* Wz = (const float*)d_in[13]; const float* bz = (const float*)d_in[14];
    const float* Wgo= (const float*)d_in[15]; const float* bgo= (const float*)d_in[16];
    const float* Wsk= (const float*)d_in[17]; const float* bsk= (const float*)d_in[18];
    const float* W3 = (const float*)d_in[19]; const float* b3 = (const float*)d_in[20];
    const float* W4 = (const float*)d_in[21]; const float* b4 = (const float*)d_in[22];

    float* ws    = (float*)d_ws;
    float* out   = (float*)d_out;
    float* gated = ws + OFF_GATED;
    float* go    = ws + OFF_GO;
    float* sk    = ws + OFF_SKIP;
    float* part  = ws + OFF_PART;
    int*   flags = (int*)(ws + OFF_FLAGS);
    int*   chs   = (int*)(ws + OFF_CHS);
    unsigned short* wzt = (unsigned short*)(ws + OFF_WZT);
    float2* carryB = (float2*)(ws + OFF_SCR);

    hipLaunchKernelGGL(k_prep, dim3(577), dim3(512), 0, stream,
                       (const unsigned char*)start, (const int*)start, flags, chs,
                       Wz, wzt, x, W1, b1, W2, b2, Wgi, bgi, Wp, bp,
                       Wgo, bgo, Wsk, bsk, gated, go, sk);
    hipLaunchKernelGGL(k_scanA, dim3(512), dim3(512), 0, stream,
                       gated, flags, a, b, carryB);
    hipLaunchKernelGGL(k_scanBZq, dim3(1024), dim3(256), 0, stream,
                       gated, flags, chs, a, b, st0, carryB, wzt, part, out);
    hipLaunchKernelGGL(k_epi, dim3(1024), dim3(256), 0, stream,
                       part, bz, go, sk, W3, b3, W4, b4, out);
}

// Round 16
// 76.907 us; speedup vs baseline: 2.2631x; 1.1238x over previous
//
#include <hip/hip_runtime.h>
#include <math.h>

#define T_LEN 4096
#define D_IN 128
#define KDIM 4096   // TR*CTX
#define K2   8192   // re+im

// ws float offsets
#define OFF_GATED 0u
#define OFF_GO    262144u
#define OFF_SKIP  524288u
#define OFF_PART  786432u          // 16 * 262144 partials
#define OFF_FLAGS 4980736u         // 4096 ints
#define OFF_CHS   4984832u         // 64 ints
#define OFF_WZT   4984896u         // 524288 bf16 = 262144 float slots
#define OFF_SCR   5247040u         // carryB 524288 floats

typedef __attribute__((ext_vector_type(8))) short short8v;
typedef __attribute__((ext_vector_type(4))) float float4v;

__device__ __forceinline__ float sigm(float x){ return 1.f/(1.f+expf(-x)); }
__device__ __forceinline__ unsigned short f2bf(float x){
    unsigned int u = __float_as_uint(x);
    return (unsigned short)((u + 0x7FFFu + ((u >> 16) & 1u)) >> 16);
}
__device__ __forceinline__ float wsum(float v) {
#pragma unroll
    for (int o = 32; o; o >>= 1) v += __shfl_xor(v, o, 64);
    return v;
}

// ---------------------------------------------------------------- prep: flags | wzt | mlp  (role by blockIdx)
__global__ __launch_bounds__(512) void k_prep(
    const unsigned char* __restrict__ su8, const int* __restrict__ si32,
    int* __restrict__ flags, int* __restrict__ chunkStart,
    const float* __restrict__ Wz, unsigned short* __restrict__ wzt,
    const float* __restrict__ x,
    const float* __restrict__ W1, const float* __restrict__ b1,
    const float* __restrict__ W2, const float* __restrict__ b2,
    const float* __restrict__ Wgi, const float* __restrict__ bgi,
    const float* __restrict__ Wp,  const float* __restrict__ bp,
    const float* __restrict__ Wgo, const float* __restrict__ bgo,
    const float* __restrict__ Wsk, const float* __restrict__ bsk,
    float* __restrict__ gated, float* __restrict__ go, float* __restrict__ sk)
{
    const int bx = blockIdx.x;
    const int tid = threadIdx.x;

    if (bx == 0) {
        __shared__ int cnt;
        if (tid == 0) cnt = 0;
        __syncthreads();
        int local = 0;
        for (int i = tid; i < 4096; i += 512)
            if (i & 3) local += su8[i];
        if (local) atomicAdd(&cnt, local);
        __syncthreads();
        if (cnt > 0) { for (int i = tid; i < 4096; i += 512) flags[i] = su8[i] ? 1 : 0; }
        else         { for (int i = tid; i < 4096; i += 512) flags[i] = si32[i] ? 1 : 0; }
        __syncthreads();
        if (tid < 64) {
            int any = 0;
#pragma unroll 8
            for (int j = 0; j < 64; ++j) any |= flags[tid * 64 + j];
            chunkStart[tid] = any;
        }
        return;
    }
    if (bx <= 64) {   // wzt[j][k] = bf16(Wz[k][j])
        int idx = ((bx - 1) * 512 + tid) * 16;
        int j = idx >> 13, k0 = idx & 8191;
#pragma unroll
        for (int e = 0; e < 16; ++e) {
            int k = k0 + e;
            wzt[(size_t)j * K2 + k] = f2bf(Wz[(size_t)k * 64 + j]);
        }
        return;
    }

    // mlp: 8 rows per block, weights-in-VGPR
    __shared__ float xs[8][128];
    __shared__ float hs[8][64];
    __shared__ float h2s[8][128];
    __shared__ float tmp[8][4][64];
    const int t0 = (bx - 65) * 8;

    if (tid < 256) {
        int r = tid >> 5, kq = (tid & 31) << 2;
        *(float4*)&xs[r][kq] = *(const float4*)&x[(size_t)(t0 + r) * D_IN + kq];
    }

    const int j1 = tid >> 3, ks1 = tid & 7;
    float wr1[16];
#pragma unroll
    for (int kk = 0; kk < 16; ++kk) wr1[kk] = W1[(size_t)(ks1 * 16 + kk) * 64 + j1];
    const float bias1 = b1[j1];
    __syncthreads();
#pragma unroll
    for (int r = 0; r < 8; ++r) {
        float p = 0.f;
#pragma unroll
        for (int kq = 0; kq < 4; ++kq) {
            float4 xv = *(const float4*)&xs[r][ks1 * 16 + kq * 4];
            p += xv.x*wr1[kq*4] + xv.y*wr1[kq*4+1] + xv.z*wr1[kq*4+2] + xv.w*wr1[kq*4+3];
        }
        p += __shfl_xor(p, 1, 64); p += __shfl_xor(p, 2, 64); p += __shfl_xor(p, 4, 64);
        if (ks1 == 0) hs[r][j1] = fmaxf(p + bias1, 0.f);
    }
    __syncthreads();

    const int j2 = tid >> 2, ks2 = tid & 3;
    float wr2[16];
#pragma unroll
    for (int kk = 0; kk < 16; ++kk) wr2[kk] = W2[(size_t)(ks2 * 16 + kk) * 128 + j2];
    const float bias2 = b2[j2];
#pragma unroll
    for (int r = 0; r < 8; ++r) {
        float p = 0.f;
#pragma unroll
        for (int kq = 0; kq < 4; ++kq) {
            float4 hv = *(const float4*)&hs[r][ks2 * 16 + kq * 4];
            p += hv.x*wr2[kq*4] + hv.y*wr2[kq*4+1] + hv.z*wr2[kq*4+2] + hv.w*wr2[kq*4+3];
        }
        p += __shfl_xor(p, 1, 64); p += __shfl_xor(p, 2, 64);
        if (ks2 == 0) h2s[r][j2] = p + bias2;
    }
    __syncthreads();

    const int mat = tid >> 7, jj = (tid & 127) >> 1, kh = tid & 1;
    const float* Wm = (mat == 0) ? Wgi : (mat == 1) ? Wp : (mat == 2) ? Wgo : Wsk;
    float wgr[64];
#pragma unroll
    for (int kk = 0; kk < 64; ++kk) wgr[kk] = Wm[(size_t)(kh * 64 + kk) * 64 + jj];
#pragma unroll
    for (int r = 0; r < 8; ++r) {
        float p = 0.f;
#pragma unroll
        for (int kq = 0; kq < 16; ++kq) {
            float4 hv = *(const float4*)&h2s[r][kh * 64 + kq * 4];
            p += hv.x*wgr[kq*4] + hv.y*wgr[kq*4+1] + hv.z*wgr[kq*4+2] + hv.w*wgr[kq*4+3];
        }
        p += __shfl_xor(p, 1, 64);
        if (kh == 0) tmp[r][mat][jj] = p;
    }
    __syncthreads();

    {
        int r = tid >> 6, j = tid & 63;
        int t = t0 + r;
        float gi = sigm(tmp[r][0][j] + bgi[j]);
        float pr = sigm(tmp[r][1][j] + bp[j]);
        float g  = sigm(tmp[r][2][j] + bgo[j]);
        float s  = tmp[r][3][j] + bsk[j];
        gated[t * 64 + j] = gi * pr;
        go[t * 64 + j]    = g;
        sk[t * 64 + j]    = s;
    }
}

// ---------------------------------------------------------------- scan A: per-chunk local carries, f32 (8 chains/block)
__global__ __launch_bounds__(512) void k_scanA(
    const float* __restrict__ gated, const int* __restrict__ flags,
    const float* __restrict__ a, const float* __restrict__ b,
    float2* __restrict__ carryB)
{
    const int p = threadIdx.x >> 6, c = threadIdx.x & 63;
    const int pair = blockIdx.x * 8 + p;
    const int ch = pair & 63, m = pair >> 6;
    const int t0 = ch * 64;

    const double ead = exp(-fabs((double)a[m]));
    const double bbd = (double)b[c];
    const float lre = (float)(ead * cos(bbd)), lim = (float)(ead * sin(bbd));
    float gv = gated[(size_t)(t0 + c) * 64 + m];
    unsigned long long fmask = __ballot(flags[t0 + c] != 0);
    float sre = 0.f, sim = 0.f;
#pragma unroll 8
    for (int j = 0; j < 64; ++j) {
        float g = __shfl(gv, j, 64);
        if ((fmask >> j) & 1) { sre = g; sim = 0.f; }
        else {
            float nr = fmaf(sre, lre, fmaf(-sim, lim, g));
            float ni = fmaf(sre, lim, sim * lre);
            sre = nr; sim = ni;
        }
    }
    carryB[(size_t)ch * KDIM + m * 64 + c] = make_float2(sre, sim);
}

// ---------------------------------------------------------------- scanBZ2: f32 prefix + 2-chunk seeded scan -> LDS -> MFMA
// grid: 512 blocks = (chpair 0..31) x (mg 0..15); 256 thr = 4 waves (ml) x 64 lanes (c)
__global__ __launch_bounds__(256) void k_scanBZ2(
    const float* __restrict__ gated, const int* __restrict__ flags,
    const int* __restrict__ chs,
    const float* __restrict__ a, const float* __restrict__ b,
    const float* __restrict__ st0,
    const float2* __restrict__ carryB,
    const unsigned short* __restrict__ wzt,
    float* __restrict__ part,
    float* __restrict__ out)
{
    const int tid = threadIdx.x;
    const int ml = tid >> 6, c = tid & 63;       // ml = wave index
    const int chpair = blockIdx.x & 31, mg = blockIdx.x >> 5;
    const int ch0 = chpair * 2;
    const int m = mg * 4 + ml;
    __shared__ unsigned short st[64 * 512];      // 64KB, swizzled chunks of 8 elems

    // per-chain lambda (f64 transcendentals, f32 arithmetic)
    const double ead = exp(-fabs((double)a[m]));
    const double bbd = (double)b[c];
    const float lre = (float)(ead * cos(bbd)), lim = (float)(ead * sin(bbd));

    // ---- carry prefix to chunk ch0: batched f32, software-pipelined (no spill)
    unsigned long long cmask = __ballot(chs[c] != 0);
    const double ea64 = exp(-64.0 * fabs((double)a[m]));
    const float l64re = (float)(ea64 * cos(64.0 * bbd));
    const float l64im = (float)(ea64 * sin(64.0 * bbd));
    float cre = st0[(m * 64 + c) * 2];
    float cim = st0[(m * 64 + c) * 2 + 1];
    {
        const float2* cbase = carryB + m * 64 + c;
        float2 BA[16], BB[16];
#define LOADB(dst, base)                                          \
        _Pragma("unroll")                                         \
        for (int q = 0; q < 16; ++q)                              \
            dst[q] = cbase[(size_t)((base) + q) * KDIM];
#define COMB(src, base)                                           \
        _Pragma("unroll")                                         \
        for (int q = 0; q < 16; ++q) {                            \
            int chp = (base) + q;                                 \
            if (chp < ch0) {  /* wave-uniform scalar branch */    \
                if ((cmask >> chp) & 1) { cre = src[q].x; cim = src[q].y; } \
                else {                                            \
                    float nr = fmaf(cre, l64re, fmaf(-cim, l64im, src[q].x)); \
                    float ni = fmaf(cre, l64im, fmaf(cim, l64re, src[q].y)); \
                    cre = nr; cim = ni;                           \
                }                                                 \
            }                                                     \
        }
        if (ch0 > 0)  { LOADB(BA, 0) }
        if (ch0 > 16) { LOADB(BB, 16) }
        if (ch0 > 0)  { COMB(BA, 0) }
        if (ch0 > 32) { LOADB(BA, 32) }
        if (ch0 > 16) { COMB(BB, 16) }
        if (ch0 > 48) { LOADB(BB, 48) }
        if (ch0 > 32) { COMB(BA, 32) }
        if (ch0 > 48) { COMB(BB, 48) }
#undef LOADB
#undef COMB
    }

    // ---- B fragments (L2-hot), shared across both chunks
    const int l = c;
    const int jrow = ml * 16 + (l & 15);
    short8v bfr[16];
#pragma unroll
    for (int ks = 0; ks < 16; ++ks)
        bfr[ks] = *(const short8v*)&wzt[(size_t)jrow * K2 + mg * 512 + (ks * 4 + (l >> 4)) * 8];

    const int e0 = ml * 128 + c, e1 = e0 + 64;
    const int jcol = ml * 16 + (l & 15);

    for (int u = 0; u < 2; ++u) {
        const int ch = ch0 + u, t0s = ch * 64;

        // ---- seeded f32 scan; running carry continues exactly across the pair
        float gv = gated[(size_t)(t0s + c) * 64 + m];
        unsigned long long fmask = __ballot(flags[t0s + c] != 0);
#pragma unroll 4
        for (int j = 0; j < 64; ++j) {
            float g = __shfl(gv, j, 64);
            if ((fmask >> j) & 1) { cre = g; cim = 0.f; }
            else {
                float nr = fmaf(cre, lre, fmaf(-cim, lim, g));
                float ni = fmaf(cre, lim, cim * lre);
                cre = nr; cim = ni;
            }
            const int sx = (j & 7) << 3;
            st[j * 512 + (e0 ^ sx)] = f2bf(cre);
            st[j * 512 + (e1 ^ sx)] = f2bf(cim);
        }
        if (ch == 63) {   // t = 4095: final state, planar f32
            out[524288 + m * 64 + c]        = cre;
            out[524288 + 4096 + m * 64 + c] = cim;
        }
        __syncthreads();

        // ---- MFMA against the tile
        float4v acc[4];
#pragma unroll
        for (int i = 0; i < 4; ++i) acc[i] = (float4v){0.f, 0.f, 0.f, 0.f};
#pragma unroll
        for (int ks = 0; ks < 16; ++ks) {
#pragma unroll
            for (int mt = 0; mt < 4; ++mt) {
                const int row = mt * 16 + (l & 15);
                const int rchunk = (ks * 4 + (l >> 4)) ^ (row & 7);
                short8v af = *(const short8v*)&st[row * 512 + rchunk * 8];
                acc[mt] = __builtin_amdgcn_mfma_f32_16x16x32_bf16(af, bfr[ks], acc[mt], 0, 0, 0);
            }
        }

        // C/D: t-row = mt*16 + (lane>>4)*4 + r; j-col = ml*16 + (lane&15)
        float* pp = part + (size_t)mg * 262144;
#pragma unroll
        for (int mt = 0; mt < 4; ++mt) {
            const int trow = t0s + mt * 16 + (l >> 4) * 4;
#pragma unroll
            for (int r = 0; r < 4; ++r)
                pp[(size_t)(trow + r) * 64 + jcol] = acc[mt][r];
        }
        __syncthreads();   // tile reuse guard before next chunk's scan overwrites st
    }
}

// ---------------------------------------------------------------- epilogue
__global__ __launch_bounds__(256) void k_epi(
    const float* __restrict__ part, const float* __restrict__ bz,
    const float* __restrict__ go, const float* __restrict__ sk,
    const float* __restrict__ W3, const float* __restrict__ b3,
    const float* __restrict__ W4, const float* __restrict__ b4,
    float* __restrict__ out)
{
    __shared__ float ob[4][64], hb[4][64];
    const int w = threadIdx.x >> 6, j = threadIdx.x & 63;
    const int t = blockIdx.x * 4 + w;
    float z = bz[j];
#pragma unroll
    for (int p = 0; p < 16; ++p) z += part[(size_t)p * 262144 + t * 64 + j];
    float g = go[t * 64 + j];
    float y = z * g;
    float mu = wsum(y) * 0.015625f;
    float d = y - mu;
    float var = wsum(d * d) * 0.015625f;
    float o = d * (1.f / sqrtf(var + 1e-6f)) + sk[t * 64 + j] * (1.f - g);
    ob[w][j] = o;
    __syncthreads();
    float acc = b3[j];
#pragma unroll 8
    for (int k = 0; k < 64; ++k) acc += ob[w][k] * W3[k * 64 + j];
    hb[w][j] = fmaxf(acc, 0.f);
    __syncthreads();
    float o1 = b4[j], o2 = b4[j + 64];
#pragma unroll 8
    for (int k = 0; k < 64; ++k) { float hv = hb[w][k]; o1 += hv * W4[k * 128 + j]; o2 += hv * W4[k * 128 + j + 64]; }
    out[(size_t)t * 128 + j] = o1;
    out[(size_t)t * 128 + j + 64] = o2;
}

// ----------------------------------------------------------------
extern "C" void kernel_launch(void* const* d_in, const int* in_sizes, int n_in,
                              void* d_out, int out_size, void* d_ws, size_t ws_size,
                              hipStream_t stream)
{
    const float* x   = (const float*)d_in[0];
    const float* st0 = (const float*)d_in[1];
    const void*  start = d_in[2];
    const float* a  = (const float*)d_in[3];
    const float* b  = (const float*)d_in[4];
    const float* W1 = (const float*)d_in[5];  const float* b1 = (const float*)d_in[6];
    const float* W2 = (const float*)d_in[7];  const float* b2 = (const float*)d_in[8];
    const float* Wgi= (const float*)d_in[9];  const float* bgi= (const float*)d_in[10];
    const float* Wp = (const float*)d_in[11]; const float* bp = (const float*)d_in[12];
    const float* Wz = (const float*)d_in[13]; const float* bz = (const float*)d_in[14];
    const float* Wgo= (const float*)d_in[15]; const float* bgo= (const float*)d_in[16];
    const float* Wsk= (const float*)d_in[17]; const float* bsk= (const float*)d_in[18];
    const float* W3 = (const float*)d_in[19]; const float* b3 = (const float*)d_in[20];
    const float* W4 = (const float*)d_in[21]; const float* b4 = (const float*)d_in[22];

    float* ws    = (float*)d_ws;
    float* out   = (float*)d_out;
    float* gated = ws + OFF_GATED;
    float* go    = ws + OFF_GO;
    float* sk    = ws + OFF_SKIP;
    float* part  = ws + OFF_PART;
    int*   flags = (int*)(ws + OFF_FLAGS);
    int*   chs   = (int*)(ws + OFF_CHS);
    unsigned short* wzt = (unsigned short*)(ws + OFF_WZT);
    float2* carryB = (float2*)(ws + OFF_SCR);

    hipLaunchKernelGGL(k_prep, dim3(577), dim3(512), 0, stream,
                       (const unsigned char*)start, (const int*)start, flags, chs,
                       Wz, wzt, x, W1, b1, W2, b2, Wgi, bgi, Wp, bp,
                       Wgo, bgo, Wsk, bsk, gated, go, sk);
    hipLaunchKernelGGL(k_scanA, dim3(512), dim3(512), 0, stream,
                       gated, flags, a, b, carryB);
    hipLaunchKernelGGL(k_scanBZ2, dim3(512), dim3(256), 0, stream,
                       gated, flags, chs, a, b, st0, carryB, wzt, part, out);
    hipLaunchKernelGGL(k_epi, dim3(1024), dim3(256), 0, stream,
                       part, bz, go, sk, W3, b3, W4, b4, out);
}